// Round 7
// baseline (350.265 us; speedup 1.0000x reference)
//
#include <hip/hip_runtime.h>
#include <hip/hip_bf16.h>

typedef __hip_bfloat16 bf16;
typedef __bf16 v8bf __attribute__((ext_vector_type(8)));
typedef float  v4f  __attribute__((ext_vector_type(4)));

struct __align__(8) bf16x4 { bf16 x, y, z, w; };

__device__ __forceinline__ bf16 f2b(float v) { return __float2bfloat16(v); }

// B=8, C=512, H=W=64 -> N=4096, HEADS=4, d=128, GROUPS=32
#define NSP 4096
#define CCH 512

// Async 16B global -> LDS (gfx950 direct-to-LDS, wave-uniform base + lane*16).
__device__ __forceinline__ void async_cp16(const bf16* g, __bf16* l) {
    __builtin_amdgcn_global_load_lds(
        (const __attribute__((address_space(1))) unsigned int*)(unsigned long long)g,
        (__attribute__((address_space(3))) unsigned int*)(unsigned int)(unsigned long long)l,
        16, 0, 0);
}

// ---------------------------------------------------------------------------
// Weight fp32 -> bf16 conversion (runs every launch; weights are re-restored).
// ---------------------------------------------------------------------------
__global__ __launch_bounds__(256) void wconv_kernel(const float* __restrict__ src,
                                                    bf16* __restrict__ dst, int n4) {
    int i = blockIdx.x * 256 + threadIdx.x;
    if (i < n4) {
        float4 v = ((const float4*)src)[i];
        bf16x4 o = { f2b(v.x), f2b(v.y), f2b(v.z), f2b(v.w) };
        ((bf16x4*)dst)[i] = o;
    }
}

// ---------------------------------------------------------------------------
// GN pass 1: per-(b,group) mean/rstd. 256 blocks.
// ---------------------------------------------------------------------------
__global__ __launch_bounds__(256) void gn_stats_kernel(const float* __restrict__ x,
                                                       float* __restrict__ stats) {
    int blk = blockIdx.x;
    int b = blk >> 5, g = blk & 31;
    size_t base = ((size_t)(b * CCH + g * 16)) * NSP;     // 65536 floats
    const float4* xp4 = (const float4*)(x + base);
    int t = threadIdx.x;
    float s = 0.f, s2 = 0.f;
    for (int i = t; i < 16384; i += 256) {
        float4 v = xp4[i];
        s  += v.x + v.y + v.z + v.w;
        s2 += v.x * v.x + v.y * v.y + v.z * v.z + v.w * v.w;
    }
    for (int off = 32; off > 0; off >>= 1) {
        s  += __shfl_down(s, off);
        s2 += __shfl_down(s2, off);
    }
    __shared__ float red[8];
    int wid = t >> 6, lid = t & 63;
    if (lid == 0) { red[wid] = s; red[wid + 4] = s2; }
    __syncthreads();
    if (t == 0) {
        float ts  = red[0] + red[1] + red[2] + red[3];
        float ts2 = red[4] + red[5] + red[6] + red[7];
        float mean = ts * (1.f / 65536.f);
        float var  = ts2 * (1.f / 65536.f) - mean * mean;
        stats[blk * 2]     = mean;
        stats[blk * 2 + 1] = rsqrtf(var + 1e-5f);
    }
}

// ---------------------------------------------------------------------------
// GN pass 2: normalize + transpose to n-major hnT[b][n][c] (bf16).
// ---------------------------------------------------------------------------
__global__ __launch_bounds__(256) void gn_norm_t_kernel(const float* __restrict__ x,
                                                        const float* __restrict__ gw,
                                                        const float* __restrict__ gb,
                                                        const float* __restrict__ stats,
                                                        bf16* __restrict__ hnT) {
    __shared__ float sT[64][65];
    int n0 = blockIdx.x * 64, c0 = blockIdx.y * 64, b = blockIdx.z;
    int t = threadIdx.x;
    int cl = t >> 4, nl4 = (t & 15) << 2;
#pragma unroll
    for (int it = 0; it < 4; ++it) {
        int crow = cl + it * 16;
        int c = c0 + crow;
        int bg = b * 32 + (c >> 4);
        float mean = stats[bg * 2], rstd = stats[bg * 2 + 1];
        float wsc = gw[c] * rstd;
        float bb  = gb[c] - mean * wsc;
        float4 v = *(const float4*)&x[((long)b * CCH + c) * NSP + n0 + nl4];
        sT[crow][nl4 + 0] = v.x * wsc + bb;
        sT[crow][nl4 + 1] = v.y * wsc + bb;
        sT[crow][nl4 + 2] = v.z * wsc + bb;
        sT[crow][nl4 + 3] = v.w * wsc + bb;
    }
    __syncthreads();
    int nl = t >> 4, cl4 = (t & 15) << 2;
#pragma unroll
    for (int it = 0; it < 4; ++it) {
        int nrow = nl + it * 16;
        bf16x4 ov = { f2b(sT[cl4 + 0][nrow]), f2b(sT[cl4 + 1][nrow]),
                      f2b(sT[cl4 + 2][nrow]), f2b(sT[cl4 + 3][nrow]) };
        *(bf16x4*)&hnT[((long)b * NSP + n0 + nrow) * CCH + c0 + cl4] = ov;
    }
}

// ---------------------------------------------------------------------------
// OLD MFMA GEMM core (m97 structure): kept for QK^T (K=512, N panel 128).
// 128x128 tile, BK=32, 256 threads (4 waves 2x2).
// ---------------------------------------------------------------------------
__device__ __forceinline__ void gemm_core(const bf16* __restrict__ A, long as,
                                          const bf16* __restrict__ B, long bs,
                                          int K, v4f acc[4][4],
                                          __bf16* sA, __bf16* sB) {
    int t = threadIdx.x;
    int lane = t & 63, wv = t >> 6;
    int wr = wv >> 1, wc = wv & 1;
    int lq = lane & 15, quad = lane >> 4;
    int r0 = wv * 16 + (lane >> 2);      // staging row, issue 0
    int koff = (lane & 3) * 8;           // staging k offset (elements)
    __bf16* ldsA0 = sA + wv * 512 + lane * 8;
    __bf16* ldsA1 = ldsA0 + 2048;
    __bf16* ldsB0 = sB + wv * 512 + lane * 8;
    __bf16* ldsB1 = ldsB0 + 2048;
    const __bf16* aBase = sA + (wr * 64) * 32;
    const __bf16* bBase = sB + (wc * 64) * 32;

    for (int k0 = 0; k0 < K; k0 += 32) {
        __syncthreads();                 // prior-iteration LDS reads done
        async_cp16(A + (long)r0 * as + k0 + koff,        ldsA0);
        async_cp16(A + (long)(r0 + 64) * as + k0 + koff, ldsA1);
        async_cp16(B + (long)r0 * bs + k0 + koff,        ldsB0);
        async_cp16(B + (long)(r0 + 64) * bs + k0 + koff, ldsB1);
        __syncthreads();                 // vmcnt drained at barrier -> data visible
        v8bf a[4], bf[4];
#pragma unroll
        for (int i = 0; i < 4; ++i)
            a[i] = *(const v8bf*)(aBase + (i * 16 + lq) * 32 + quad * 8);
#pragma unroll
        for (int j = 0; j < 4; ++j)
            bf[j] = *(const v8bf*)(bBase + (j * 16 + lq) * 32 + quad * 8);
#pragma unroll
        for (int i = 0; i < 4; ++i)
#pragma unroll
            for (int j = 0; j < 4; ++j)
                acc[i][j] = __builtin_amdgcn_mfma_f32_16x16x32_bf16(a[i], bf[j], acc[i][j], 0, 0, 0);
    }
}

// ---------------------------------------------------------------------------
// 256x256 GEMM core (round-5 schedule, best measured): used by proj.
//   Stage: ph1/2 -> T{k+1}.A halves (nxt buf); ph3/4 -> T{k+2}.B halves (cur).
//   Boundary vmcnt(4). Swizzle byte^=((row&7)<<4) src-side + ds_read-side.
// ---------------------------------------------------------------------------
__device__ __forceinline__ void gemm256_core(const bf16* __restrict__ A, long lda,
                                             const bf16* __restrict__ B, long ldb,
                                             int K, v4f acc[8][4], char* sLds) {
    const int t = threadIdx.x;
    const int lane = t & 63, wv = t >> 6;
    const int wm = wv >> 2, wn = wv & 3;
    const int lq = lane & 15, quad = lane >> 4;
    const int xsw = (lq & 7) << 4;
    const int kq0 = ((quad << 4)) ^ xsw;
    const int kq1 = (64 | (quad << 4)) ^ xsw;
    const int aRow0 = (wm * 128 + lq) << 7;
    const int bRow0 = (wn * 64 + lq) << 7;
    const int NT = K >> 6;

    auto STAGE = [&](const bf16* mb, long ld, int ldsbyte, int ktile, int h) {
#pragma unroll
        for (int s = 0; s < 2; ++s) {
            int L = (s << 13) + (t << 4);
            int row = L >> 7;
            int kb = (L & 127) ^ ((row & 7) << 4);
            const char* g = (const char*)(mb + (long)(h * 128 + row) * ld + (long)ktile * 64);
            async_cp16((const bf16*)(g + kb),
                       (__bf16*)(sLds + ldsbyte + (h << 14) + L));
        }
    };

    STAGE(B, ldb, 32768, 0, 0);
    STAGE(B, ldb, 32768, 0, 1);
    STAGE(A, lda, 0,     0, 0);
    STAGE(A, lda, 0,     0, 1);
    if (NT > 1) {
        STAGE(B, ldb, 65536 + 32768, 1, 0);
        STAGE(B, ldb, 65536 + 32768, 1, 1);
        asm volatile("s_waitcnt vmcnt(4)" ::: "memory");
    } else {
        asm volatile("s_waitcnt vmcnt(0)" ::: "memory");
    }
    __builtin_amdgcn_s_barrier();
    asm volatile("" ::: "memory");

    for (int kt = 0; kt < NT; ++kt) {
        const int cb = (kt & 1) << 16;
        const int nb = cb ^ 65536;
        const int bufA = cb, bufB = cb | 32768;
        v8bf a[4][2], b0[2][2], b1[2][2];

#pragma unroll
        for (int ii = 0; ii < 4; ++ii) {
            a[ii][0] = *(const v8bf*)(sLds + bufA + aRow0 + ((ii * 16) << 7) + kq0);
            a[ii][1] = *(const v8bf*)(sLds + bufA + aRow0 + ((ii * 16) << 7) + kq1);
        }
#pragma unroll
        for (int jj = 0; jj < 2; ++jj) {
            b0[jj][0] = *(const v8bf*)(sLds + bufB + bRow0 + ((jj * 16) << 7) + kq0);
            b0[jj][1] = *(const v8bf*)(sLds + bufB + bRow0 + ((jj * 16) << 7) + kq1);
        }
        if (kt + 1 < NT) STAGE(A, lda, nb, kt + 1, 0);
        __builtin_amdgcn_s_setprio(1);
#pragma unroll
        for (int ii = 0; ii < 4; ++ii)
#pragma unroll
            for (int jj = 0; jj < 2; ++jj) {
                acc[ii][jj] = __builtin_amdgcn_mfma_f32_16x16x32_bf16(a[ii][0], b0[jj][0], acc[ii][jj], 0, 0, 0);
                acc[ii][jj] = __builtin_amdgcn_mfma_f32_16x16x32_bf16(a[ii][1], b0[jj][1], acc[ii][jj], 0, 0, 0);
            }
        __builtin_amdgcn_s_setprio(0);
        __builtin_amdgcn_s_barrier();
        asm volatile("" ::: "memory");

#pragma unroll
        for (int jj = 0; jj < 2; ++jj) {
            b1[jj][0] = *(const v8bf*)(sLds + bufB + bRow0 + ((32 + jj * 16) << 7) + kq0);
            b1[jj][1] = *(const v8bf*)(sLds + bufB + bRow0 + ((32 + jj * 16) << 7) + kq1);
        }
        if (kt + 1 < NT) STAGE(A, lda, nb, kt + 1, 1);
        __builtin_amdgcn_s_setprio(1);
#pragma unroll
        for (int ii = 0; ii < 4; ++ii)
#pragma unroll
            for (int jj = 0; jj < 2; ++jj) {
                acc[ii][2 + jj] = __builtin_amdgcn_mfma_f32_16x16x32_bf16(a[ii][0], b1[jj][0], acc[ii][2 + jj], 0, 0, 0);
                acc[ii][2 + jj] = __builtin_amdgcn_mfma_f32_16x16x32_bf16(a[ii][1], b1[jj][1], acc[ii][2 + jj], 0, 0, 0);
            }
        __builtin_amdgcn_s_setprio(0);
        __builtin_amdgcn_s_barrier();
        asm volatile("" ::: "memory");

#pragma unroll
        for (int ii = 0; ii < 4; ++ii) {
            a[ii][0] = *(const v8bf*)(sLds + bufA + aRow0 + ((64 + ii * 16) << 7) + kq0);
            a[ii][1] = *(const v8bf*)(sLds + bufA + aRow0 + ((64 + ii * 16) << 7) + kq1);
        }
        if (kt + 2 < NT) STAGE(B, ldb, bufB, kt + 2, 0);
        __builtin_amdgcn_s_setprio(1);
#pragma unroll
        for (int ii = 0; ii < 4; ++ii)
#pragma unroll
            for (int jj = 0; jj < 2; ++jj) {
                acc[4 + ii][2 + jj] = __builtin_amdgcn_mfma_f32_16x16x32_bf16(a[ii][0], b1[jj][0], acc[4 + ii][2 + jj], 0, 0, 0);
                acc[4 + ii][2 + jj] = __builtin_amdgcn_mfma_f32_16x16x32_bf16(a[ii][1], b1[jj][1], acc[4 + ii][2 + jj], 0, 0, 0);
            }
        __builtin_amdgcn_s_setprio(0);
        __builtin_amdgcn_s_barrier();
        asm volatile("" ::: "memory");

        if (kt + 2 < NT) STAGE(B, ldb, bufB, kt + 2, 1);
        __builtin_amdgcn_s_setprio(1);
#pragma unroll
        for (int ii = 0; ii < 4; ++ii)
#pragma unroll
            for (int jj = 0; jj < 2; ++jj) {
                acc[4 + ii][jj] = __builtin_amdgcn_mfma_f32_16x16x32_bf16(a[ii][0], b0[jj][0], acc[4 + ii][jj], 0, 0, 0);
                acc[4 + ii][jj] = __builtin_amdgcn_mfma_f32_16x16x32_bf16(a[ii][1], b0[jj][1], acc[4 + ii][jj], 0, 0, 0);
            }
        __builtin_amdgcn_s_setprio(0);
        if (kt + 2 < NT) asm volatile("s_waitcnt vmcnt(4)" ::: "memory");
        else             asm volatile("s_waitcnt vmcnt(0)" ::: "memory");
        __builtin_amdgcn_s_barrier();
        asm volatile("" ::: "memory");
    }
}

// ---------------------------------------------------------------------------
// QKV GEMM, PERSISTENT: grid = 256 blocks (1/CU), each handles 3 consecutive
// linear tiles l = 3p+i, l -> (b = (l>>4)/6, o0 = ((l>>4)%6)*256, n0 =
// (l&15)*256). Flat 24-K-tile pipeline with round-5 schedule; cross-tile
// staging at kt=6/7 fills the next tile's T0/T1 so tile transitions and
// epilogues fully overlap in-flight loads. Boundary vmcnt(4) throughout.
// ---------------------------------------------------------------------------
__global__ __launch_bounds__(512, 2) void qkv_gemm_kernel(const bf16* __restrict__ hnT,
                                                          const bf16* __restrict__ qkv_wb,
                                                          const float* __restrict__ qkv_b,
                                                          bf16* __restrict__ qkbuf,
                                                          bf16* __restrict__ vT) {
    __shared__ __align__(16) char sLds[131072];
    const int p = blockIdx.x;
    const int t = threadIdx.x;
    const int lane = t & 63, wv = t >> 6;
    const int wm = wv >> 2, wn = wv & 3;
    const int lq = lane & 15, quad = lane >> 4;
    const int xsw = (lq & 7) << 4;
    const int kq0 = ((quad << 4)) ^ xsw;
    const int kq1 = (64 | (quad << 4)) ^ xsw;
    const int aRow0 = (wm * 128 + lq) << 7;
    const int bRow0 = (wn * 64 + lq) << 7;

    auto decodeA = [&](int l) -> const bf16* {
        int n0 = (l & 15) << 8; int b = (l >> 4) / 6;
        return hnT + ((long)b * NSP + n0) * CCH;
    };
    auto decodeB = [&](int l) -> const bf16* {
        int o0 = ((l >> 4) % 6) << 8;
        return qkv_wb + (long)o0 * CCH;
    };

    auto STAGE = [&](const bf16* mb, int ldsbyte, int ktile, int h) {
#pragma unroll
        for (int s = 0; s < 2; ++s) {
            int L = (s << 13) + (t << 4);
            int row = L >> 7;
            int kb = (L & 127) ^ ((row & 7) << 4);
            const char* g = (const char*)(mb + (long)(h * 128 + row) * CCH + (long)ktile * 64);
            async_cp16((const bf16*)(g + kb),
                       (__bf16*)(sLds + ldsbyte + (h << 14) + L));
        }
    };

    const int l0 = p * 3;
    const bf16* Acur = decodeA(l0);
    const bf16* Bcur = decodeB(l0);
    const bf16* Anxt = decodeA(l0 + 1);
    const bf16* Bnxt = decodeB(l0 + 1);

    v4f acc[8][4] = {};

    // Prologue: T0 (B,A) -> buf0; T1.B -> buf1 (T1.A staged in kt=0 ph1/2).
    STAGE(Bcur, 32768, 0, 0);
    STAGE(Bcur, 32768, 0, 1);
    STAGE(Acur, 0,     0, 0);
    STAGE(Acur, 0,     0, 1);
    STAGE(Bcur, 65536 + 32768, 1, 0);
    STAGE(Bcur, 65536 + 32768, 1, 1);
    asm volatile("s_waitcnt vmcnt(4)" ::: "memory");   // T0's 8 loads landed
    __builtin_amdgcn_s_barrier();
    asm volatile("" ::: "memory");

    for (int ti = 0; ti < 3; ++ti) {
        for (int kt = 0; kt < 8; ++kt) {
            const int cb = (kt & 1) << 16;
            const int nb = cb ^ 65536;
            const int bufA = cb, bufB = cb | 32768;
            v8bf a[4][2], b0[2][2], b1[2][2];

            // staging sources: A for K-tile g+1, B for K-tile g+2 (flat g).
            const bf16* As = (kt < 7) ? Acur : Anxt;
            const int   Akt = (kt < 7) ? kt + 1 : 0;
            const bool  doA = !(ti == 2 && kt == 7);
            const bf16* Bs = (kt < 6) ? Bcur : Bnxt;
            const int   Bkt = (kt < 6) ? kt + 2 : kt - 6;
            const bool  doB = !(ti == 2 && kt >= 6);

            // ---- phase 1: read A-quad0 + B-quad0; stage A(g+1).h0; MFMA ----
#pragma unroll
            for (int ii = 0; ii < 4; ++ii) {
                a[ii][0] = *(const v8bf*)(sLds + bufA + aRow0 + ((ii * 16) << 7) + kq0);
                a[ii][1] = *(const v8bf*)(sLds + bufA + aRow0 + ((ii * 16) << 7) + kq1);
            }
#pragma unroll
            for (int jj = 0; jj < 2; ++jj) {
                b0[jj][0] = *(const v8bf*)(sLds + bufB + bRow0 + ((jj * 16) << 7) + kq0);
                b0[jj][1] = *(const v8bf*)(sLds + bufB + bRow0 + ((jj * 16) << 7) + kq1);
            }
            if (doA) STAGE(As, nb, Akt, 0);
            __builtin_amdgcn_s_setprio(1);
#pragma unroll
            for (int ii = 0; ii < 4; ++ii)
#pragma unroll
                for (int jj = 0; jj < 2; ++jj) {
                    acc[ii][jj] = __builtin_amdgcn_mfma_f32_16x16x32_bf16(a[ii][0], b0[jj][0], acc[ii][jj], 0, 0, 0);
                    acc[ii][jj] = __builtin_amdgcn_mfma_f32_16x16x32_bf16(a[ii][1], b0[jj][1], acc[ii][jj], 0, 0, 0);
                }
            __builtin_amdgcn_s_setprio(0);
            __builtin_amdgcn_s_barrier();
            asm volatile("" ::: "memory");

            // ---- phase 2: read B-quad1; stage A(g+1).h1; MFMA, reuse a ----
#pragma unroll
            for (int jj = 0; jj < 2; ++jj) {
                b1[jj][0] = *(const v8bf*)(sLds + bufB + bRow0 + ((32 + jj * 16) << 7) + kq0);
                b1[jj][1] = *(const v8bf*)(sLds + bufB + bRow0 + ((32 + jj * 16) << 7) + kq1);
            }
            if (doA) STAGE(As, nb, Akt, 1);
            __builtin_amdgcn_s_setprio(1);
#pragma unroll
            for (int ii = 0; ii < 4; ++ii)
#pragma unroll
                for (int jj = 0; jj < 2; ++jj) {
                    acc[ii][2 + jj] = __builtin_amdgcn_mfma_f32_16x16x32_bf16(a[ii][0], b1[jj][0], acc[ii][2 + jj], 0, 0, 0);
                    acc[ii][2 + jj] = __builtin_amdgcn_mfma_f32_16x16x32_bf16(a[ii][1], b1[jj][1], acc[ii][2 + jj], 0, 0, 0);
                }
            __builtin_amdgcn_s_setprio(0);
            __builtin_amdgcn_s_barrier();
            asm volatile("" ::: "memory");

            // ---- phase 3: read A-quad1; stage B(g+2).h0 -> cur.bufB; MFMA --
#pragma unroll
            for (int ii = 0; ii < 4; ++ii) {
                a[ii][0] = *(const v8bf*)(sLds + bufA + aRow0 + ((64 + ii * 16) << 7) + kq0);
                a[ii][1] = *(const v8bf*)(sLds + bufA + aRow0 + ((64 + ii * 16) << 7) + kq1);
            }
            if (doB) STAGE(Bs, bufB, Bkt, 0);
            __builtin_amdgcn_s_setprio(1);
#pragma unroll
            for (int ii = 0; ii < 4; ++ii)
#pragma unroll
                for (int jj = 0; jj < 2; ++jj) {
                    acc[4 + ii][2 + jj] = __builtin_amdgcn_mfma_f32_16x16x32_bf16(a[ii][0], b1[jj][0], acc[4 + ii][2 + jj], 0, 0, 0);
                    acc[4 + ii][2 + jj] = __builtin_amdgcn_mfma_f32_16x16x32_bf16(a[ii][1], b1[jj][1], acc[4 + ii][2 + jj], 0, 0, 0);
                }
            __builtin_amdgcn_s_setprio(0);
            __builtin_amdgcn_s_barrier();
            asm volatile("" ::: "memory");

            // ---- phase 4: stage B(g+2).h1; MFMA, reuse a + b0 ----
            if (doB) STAGE(Bs, bufB, Bkt, 1);
            __builtin_amdgcn_s_setprio(1);
#pragma unroll
            for (int ii = 0; ii < 4; ++ii)
#pragma unroll
                for (int jj = 0; jj < 2; ++jj) {
                    acc[4 + ii][jj] = __builtin_amdgcn_mfma_f32_16x16x32_bf16(a[ii][0], b0[jj][0], acc[4 + ii][jj], 0, 0, 0);
                    acc[4 + ii][jj] = __builtin_amdgcn_mfma_f32_16x16x32_bf16(a[ii][1], b0[jj][1], acc[4 + ii][jj], 0, 0, 0);
                }
            __builtin_amdgcn_s_setprio(0);
            // Boundary: retire K-tile g+1's loads; keep g+2's in flight.
            if (doB) asm volatile("s_waitcnt vmcnt(4)" ::: "memory");
            else     asm volatile("s_waitcnt vmcnt(0)" ::: "memory");
            __builtin_amdgcn_s_barrier();
            asm volatile("" ::: "memory");
        }

        // ---- epilogue for tile l0+ti (overlaps next tile's in-flight loads)
        {
            int l = l0 + ti;
            int n0 = (l & 15) << 8;
            int oc = l >> 4;
            int o0 = (oc % 6) << 8;
            int b  = oc / 6;
            if (o0 < 1024) {
#pragma unroll
                for (int j = 0; j < 4; ++j) {
                    int o = o0 + wn * 64 + j * 16 + lq;
                    float bias = qkv_b[o];
#pragma unroll
                    for (int i = 0; i < 8; ++i) {
                        int n = n0 + wm * 128 + i * 16 + quad * 4;
                        v4f v = acc[i][j];
                        bf16x4 ov = { f2b(v[0] + bias), f2b(v[1] + bias),
                                      f2b(v[2] + bias), f2b(v[3] + bias) };
                        *(bf16x4*)&qkbuf[((long)b * 1024 + o) * NSP + n] = ov;
                    }
                }
            } else {
#pragma unroll
                for (int j = 0; j < 4; ++j) {
                    int e = o0 - 1024 + wn * 64 + j * 16 + lq;
                    float bias = qkv_b[1024 + e];
#pragma unroll
                    for (int i = 0; i < 8; ++i) {
                        int n = n0 + wm * 128 + i * 16 + quad * 4;
                        v4f v = acc[i][j];
#pragma unroll
                        for (int r = 0; r < 4; ++r)
                            vT[((long)b * NSP + n + r) * CCH + e] = f2b(v[r] + bias);
                    }
                }
            }
            if (ti < 2) {
#pragma unroll
                for (int i = 0; i < 8; ++i)
#pragma unroll
                    for (int j = 0; j < 4; ++j)
                        acc[i][j] = (v4f){0.f, 0.f, 0.f, 0.f};
                Acur = Anxt; Bcur = Bnxt;
                if (ti == 0) { Anxt = decodeA(l0 + 2); Bnxt = decodeB(l0 + 2); }
            }
        }
    }
}

// ---------------------------------------------------------------------------
// QK^T split-K: P_part[s][bh][d][e] = sum_{n in split} q[d][n]*k[e][n]
// grid (8 splits, 32 bh) -- old core (N panel = 128 only)
// ---------------------------------------------------------------------------
__global__ __launch_bounds__(256) void qk_gemm_kernel(const bf16* __restrict__ qkbuf,
                                                      float* __restrict__ P_part) {
    __shared__ __align__(16) __bf16 sA[128 * 32];
    __shared__ __align__(16) __bf16 sB[128 * 32];
    int s = blockIdx.x, bh = blockIdx.y;
    int b = bh >> 2, h = bh & 3;
    const bf16* q  = qkbuf + ((long)b * 1024 + h * 128) * NSP + s * 512;
    const bf16* kk = qkbuf + ((long)b * 1024 + 512 + h * 128) * NSP + s * 512;
    v4f acc[4][4] = {};
    gemm_core(q, NSP, kk, NSP, 512, acc, sA, sB);
    float* Pp = P_part + ((long)s * 32 + bh) * 16384;
    int t = threadIdx.x, lane = t & 63, wv = t >> 6, wr = wv >> 1, wc = wv & 1;
    int lq = lane & 15, quad = lane >> 4;
#pragma unroll
    for (int j = 0; j < 4; ++j) {
        int e = wc * 64 + j * 16 + lq;
#pragma unroll
        for (int i = 0; i < 4; ++i) {
            int d = wr * 64 + i * 16 + quad * 4;
            v4f v = acc[i][j];
#pragma unroll
            for (int r = 0; r < 4; ++r) Pp[(long)(d + r) * 128 + e] = v[r];
        }
    }
}

// ---------------------------------------------------------------------------
// Softmax: sum 8 partials, scale by d^-0.5, softmax over e, emit bf16 P.
// ---------------------------------------------------------------------------
__global__ __launch_bounds__(128) void softmax_kernel(const float* __restrict__ P_part,
                                                      bf16* __restrict__ Pb) {
    int row = blockIdx.x;
    int bh = row >> 7, d = row & 127;
    int t = threadIdx.x;
    float v = 0.f;
#pragma unroll
    for (int s = 0; s < 8; ++s)
        v += P_part[((long)s * 32 + bh) * 16384 + (long)d * 128 + t];
    v *= 0.08838834764831845f;
    float m = v;
    for (int off = 32; off > 0; off >>= 1) m = fmaxf(m, __shfl_down(m, off));
    __shared__ float sm[2];
    if ((t & 63) == 0) sm[t >> 6] = m;
    __syncthreads();
    m = fmaxf(sm[0], sm[1]);
    float e = __expf(v - m);
    float ssum = e;
    for (int off = 32; off > 0; off >>= 1) ssum += __shfl_down(ssum, off);
    __shared__ float ss[2];
    if ((t & 63) == 0) ss[t >> 6] = ssum;
    __syncthreads();
    ssum = ss[0] + ss[1];
    Pb[(long)row * 128 + t] = f2b(e / ssum);
}

// ---------------------------------------------------------------------------
// PV v2 (persistent P): attT[b][n][h*128+d] = sum_e P[d][e] * vT[n][e].
// P (32 KB, L2-hot) -> registers once per block; vT tiles staged in LDS
// (swizzled, double-buffered 2x32KB -> 2 blocks/CU).
// grid (16 n-groups x 32 bh), 256 threads (4 waves 2x2), 2 n-tiles/block.
// ---------------------------------------------------------------------------
__global__ __launch_bounds__(256) void pv_gemm_kernel(const bf16* __restrict__ Pb,
                                                      const bf16* __restrict__ vT,
                                                      bf16* __restrict__ attT) {
    __shared__ __align__(16) char sV[2][32768];
    int ng = blockIdx.x, bh = blockIdx.y;
    int b = bh >> 2, h = bh & 3;
    int t = threadIdx.x, lane = t & 63, wv = t >> 6, wr = wv >> 1, wc = wv & 1;
    int lq = lane & 15, quad = lane >> 4;

    auto STAGEV = [&](int n0, int buf) {
#pragma unroll
        for (int s = 0; s < 8; ++s) {
            int L = (s << 12) + (t << 4);
            int row = L >> 8;
            int col = (L & 255) ^ ((row & 7) << 4);
            async_cp16((const bf16*)((const char*)(vT + ((long)b * NSP + n0 + row) * CCH + h * 128) + col),
                       (__bf16*)(&sV[buf][0] + L));
        }
    };

    int n00 = ng * 256;
    STAGEV(n00, 0);
    v8bf a[4][4];
    const char* Pp = (const char*)(Pb + (long)bh * 16384);
#pragma unroll
    for (int i = 0; i < 4; ++i)
#pragma unroll
        for (int ks = 0; ks < 4; ++ks)
            a[i][ks] = *(const v8bf*)(Pp + ((wr * 64 + i * 16 + lq) << 8) + (ks << 6) + (quad << 4));
    STAGEV(n00 + 128, 1);
    asm volatile("s_waitcnt vmcnt(8)" ::: "memory");
    __syncthreads();

#pragma unroll
    for (int nt = 0; nt < 2; ++nt) {
        int n0 = n00 + nt * 128;
        const char* base = &sV[nt][0];
        v4f acc[4][4] = {};
#pragma unroll
        for (int ks = 0; ks < 4; ++ks) {
            v8bf bv[4];
#pragma unroll
            for (int j = 0; j < 4; ++j) {
                int r = wc * 64 + j * 16 + lq;
                bv[j] = *(const v8bf*)(base + (r << 8) + (((ks << 6) + (quad << 4)) ^ ((r & 7) << 4)));
            }
#pragma unroll
            for (int i = 0; i < 4; ++i)
#pragma unroll
                for (int j = 0; j < 4; ++j)
                    acc[i][j] = __builtin_amdgcn_mfma_f32_16x16x32_bf16(a[i][ks], bv[j], acc[i][j], 0, 0, 0);
        }
#pragma unroll
        for (int j = 0; j < 4; ++j) {
            int n = n0 + wc * 64 + j * 16 + lq;
#pragma unroll
            for (int i = 0; i < 4; ++i) {
                int d = wr * 64 + i * 16 + quad * 4;
                v4f v = acc[i][j];
                bf16x4 ov = { f2b(v[0]), f2b(v[1]), f2b(v[2]), f2b(v[3]) };
                *(bf16x4*)&attT[((long)b * NSP + n) * CCH + h * 128 + d] = ov;
            }
        }
        if (nt == 0) {
            asm volatile("s_waitcnt vmcnt(0)" ::: "memory");
            __syncthreads();
        }
    }
}

// ---------------------------------------------------------------------------
// Proj (swapped): out[b][c][n] = sum_k attT[n][k]*Wp[c][k] + bias[c] + x
// 256x256 tiles: grid (16 n-tiles, 2 c-tiles, 8 b), 512 threads.
// ---------------------------------------------------------------------------
__global__ __launch_bounds__(512, 2) void proj_gemm_kernel(const bf16* __restrict__ attT,
                                                           const bf16* __restrict__ proj_wb,
                                                           const float* __restrict__ proj_b,
                                                           const float* __restrict__ x,
                                                           float* __restrict__ out) {
    __shared__ __align__(16) char sLds[131072];
    int n0 = blockIdx.x * 256, c0 = blockIdx.y * 256, b = blockIdx.z;
    v4f acc[8][4] = {};
    gemm256_core(attT + ((long)b * NSP + n0) * CCH, CCH,
                 proj_wb + (long)c0 * CCH, CCH, CCH, acc, sLds);
    int t = threadIdx.x, lane = t & 63, wv = t >> 6, wm = wv >> 2, wn = wv & 3;
    int lq = lane & 15, quad = lane >> 4;
#pragma unroll
    for (int j = 0; j < 4; ++j) {
        int c = c0 + wn * 64 + j * 16 + lq;
        float bias = proj_b[c];
#pragma unroll
        for (int i = 0; i < 8; ++i) {
            int n = n0 + wm * 128 + i * 16 + quad * 4;
            long idx = ((long)b * CCH + c) * NSP + n;
            float4 r = *(const float4*)&x[idx];
            v4f v = acc[i][j];
            float4 ov = { v[0] + bias + r.x, v[1] + bias + r.y,
                          v[2] + bias + r.z, v[3] + bias + r.w };
            *(float4*)&out[idx] = ov;
        }
    }
}

// ---------------------------------------------------------------------------
extern "C" void kernel_launch(void* const* d_in, const int* in_sizes, int n_in,
                              void* d_out, int out_size, void* d_ws, size_t ws_size,
                              hipStream_t stream) {
    const float* x      = (const float*)d_in[0];
    const float* gn_w   = (const float*)d_in[1];
    const float* gn_b   = (const float*)d_in[2];
    const float* qkv_w  = (const float*)d_in[3];
    const float* qkv_b  = (const float*)d_in[4];
    const float* proj_w = (const float*)d_in[5];
    const float* proj_b = (const float*)d_in[6];
    float* out = (float*)d_out;

    char* ws = (char*)d_ws;
    // region0 (33.5 MB) reused over time: hnT -> P_part -> attT
    bf16*  hnT    = (bf16*)ws;
    float* P_part = (float*)ws;                    // 8*32*128*128 fp32 = 16.8 MB
    bf16*  attT   = (bf16*)ws;
    bf16*  qkbuf  = (bf16*)(ws + 33554432);        // [b][1024][4096] bf16 = 67.1 MB
    bf16*  vT     = (bf16*)(ws + 100663296);       // [b][4096][512]  bf16 = 33.5 MB
    bf16*  Pb     = (bf16*)(ws + 134217728);       // 32*128*128 bf16 = 1 MB
    float* stats  = (float*)(ws + 135266304);      // 256*2 fp32
    bf16*  qkv_wb = (bf16*)(ws + 135270400);       // 1536*512 bf16 = 1.5 MB
    bf16*  proj_wb= (bf16*)(ws + 136843264);       // 512*512 bf16 = 0.5 MB

    wconv_kernel<<<768, 256, 0, stream>>>(qkv_w, qkv_wb, 196608);
    wconv_kernel<<<256, 256, 0, stream>>>(proj_w, proj_wb, 65536);
    gn_stats_kernel<<<256, 256, 0, stream>>>(x, stats);
    gn_norm_t_kernel<<<dim3(64, 8, 8), 256, 0, stream>>>(x, gn_w, gn_b, stats, hnT);
    qkv_gemm_kernel<<<256, 512, 0, stream>>>(hnT, qkv_wb, qkv_b, qkbuf, vT);
    qk_gemm_kernel<<<dim3(8, 32), 256, 0, stream>>>(qkbuf, P_part);
    softmax_kernel<<<4096, 128, 0, stream>>>(P_part, Pb);
    pv_gemm_kernel<<<dim3(16, 32), 256, 0, stream>>>(Pb, vT, attT);
    proj_gemm_kernel<<<dim3(16, 2, 8), 512, 0, stream>>>(attT, proj_wb, proj_b, x, out);
}

// Round 8
// 301.747 us; speedup vs baseline: 1.1608x; 1.1608x over previous
//
#include <hip/hip_runtime.h>
#include <hip/hip_bf16.h>

typedef __hip_bfloat16 bf16;
typedef __bf16 v8bf __attribute__((ext_vector_type(8)));
typedef float  v4f  __attribute__((ext_vector_type(4)));

struct __align__(8) bf16x4 { bf16 x, y, z, w; };

__device__ __forceinline__ bf16 f2b(float v) { return __float2bfloat16(v); }

// B=8, C=512, H=W=64 -> N=4096, HEADS=4, d=128, GROUPS=32
#define NSP 4096
#define CCH 512

// Async 16B global -> LDS (gfx950 direct-to-LDS, wave-uniform base + lane*16).
__device__ __forceinline__ void async_cp16(const bf16* g, __bf16* l) {
    __builtin_amdgcn_global_load_lds(
        (const __attribute__((address_space(1))) unsigned int*)(unsigned long long)g,
        (__attribute__((address_space(3))) unsigned int*)(unsigned int)(unsigned long long)l,
        16, 0, 0);
}

// ---------------------------------------------------------------------------
// Weight fp32 -> bf16 conversion, both weight tensors in one launch.
// ---------------------------------------------------------------------------
__global__ __launch_bounds__(256) void wconv2_kernel(const float* __restrict__ qw,
                                                     const float* __restrict__ pw,
                                                     bf16* __restrict__ qd,
                                                     bf16* __restrict__ pd) {
    int i = blockIdx.x * 256 + threadIdx.x;
    if (i < 196608) {
        float4 v = ((const float4*)qw)[i];
        bf16x4 o = { f2b(v.x), f2b(v.y), f2b(v.z), f2b(v.w) };
        ((bf16x4*)qd)[i] = o;
    } else {
        int j = i - 196608;
        float4 v = ((const float4*)pw)[j];
        bf16x4 o = { f2b(v.x), f2b(v.y), f2b(v.z), f2b(v.w) };
        ((bf16x4*)pd)[j] = o;
    }
}

// ---------------------------------------------------------------------------
// GN pass 1: per-(b,group) mean/rstd. 256 blocks.
// ---------------------------------------------------------------------------
__global__ __launch_bounds__(256) void gn_stats_kernel(const float* __restrict__ x,
                                                       float* __restrict__ stats) {
    int blk = blockIdx.x;
    int b = blk >> 5, g = blk & 31;
    size_t base = ((size_t)(b * CCH + g * 16)) * NSP;     // 65536 floats
    const float4* xp4 = (const float4*)(x + base);
    int t = threadIdx.x;
    float s = 0.f, s2 = 0.f;
    for (int i = t; i < 16384; i += 256) {
        float4 v = xp4[i];
        s  += v.x + v.y + v.z + v.w;
        s2 += v.x * v.x + v.y * v.y + v.z * v.z + v.w * v.w;
    }
    for (int off = 32; off > 0; off >>= 1) {
        s  += __shfl_down(s, off);
        s2 += __shfl_down(s2, off);
    }
    __shared__ float red[8];
    int wid = t >> 6, lid = t & 63;
    if (lid == 0) { red[wid] = s; red[wid + 4] = s2; }
    __syncthreads();
    if (t == 0) {
        float ts  = red[0] + red[1] + red[2] + red[3];
        float ts2 = red[4] + red[5] + red[6] + red[7];
        float mean = ts * (1.f / 65536.f);
        float var  = ts2 * (1.f / 65536.f) - mean * mean;
        stats[blk * 2]     = mean;
        stats[blk * 2 + 1] = rsqrtf(var + 1e-5f);
    }
}

// ---------------------------------------------------------------------------
// GN pass 2: normalize + transpose to n-major hnT[b][n][c] (bf16).
// ---------------------------------------------------------------------------
__global__ __launch_bounds__(256) void gn_norm_t_kernel(const float* __restrict__ x,
                                                        const float* __restrict__ gw,
                                                        const float* __restrict__ gb,
                                                        const float* __restrict__ stats,
                                                        bf16* __restrict__ hnT) {
    __shared__ float sT[64][65];
    int n0 = blockIdx.x * 64, c0 = blockIdx.y * 64, b = blockIdx.z;
    int t = threadIdx.x;
    int cl = t >> 4, nl4 = (t & 15) << 2;
#pragma unroll
    for (int it = 0; it < 4; ++it) {
        int crow = cl + it * 16;
        int c = c0 + crow;
        int bg = b * 32 + (c >> 4);
        float mean = stats[bg * 2], rstd = stats[bg * 2 + 1];
        float wsc = gw[c] * rstd;
        float bb  = gb[c] - mean * wsc;
        float4 v = *(const float4*)&x[((long)b * CCH + c) * NSP + n0 + nl4];
        sT[crow][nl4 + 0] = v.x * wsc + bb;
        sT[crow][nl4 + 1] = v.y * wsc + bb;
        sT[crow][nl4 + 2] = v.z * wsc + bb;
        sT[crow][nl4 + 3] = v.w * wsc + bb;
    }
    __syncthreads();
    int nl = t >> 4, cl4 = (t & 15) << 2;
#pragma unroll
    for (int it = 0; it < 4; ++it) {
        int nrow = nl + it * 16;
        bf16x4 ov = { f2b(sT[cl4 + 0][nrow]), f2b(sT[cl4 + 1][nrow]),
                      f2b(sT[cl4 + 2][nrow]), f2b(sT[cl4 + 3][nrow]) };
        *(bf16x4*)&hnT[((long)b * NSP + n0 + nrow) * CCH + c0 + cl4] = ov;
    }
}

// ---------------------------------------------------------------------------
// OLD MFMA GEMM core (m97 structure): used by QK^T and PV.
// 128x128 tile, BK=32, 256 threads (4 waves 2x2).
// ---------------------------------------------------------------------------
__device__ __forceinline__ void gemm_core(const bf16* __restrict__ A, long as,
                                          const bf16* __restrict__ B, long bs,
                                          int K, v4f acc[4][4],
                                          __bf16* sA, __bf16* sB) {
    int t = threadIdx.x;
    int lane = t & 63, wv = t >> 6;
    int wr = wv >> 1, wc = wv & 1;
    int lq = lane & 15, quad = lane >> 4;
    int r0 = wv * 16 + (lane >> 2);      // staging row, issue 0
    int koff = (lane & 3) * 8;           // staging k offset (elements)
    __bf16* ldsA0 = sA + wv * 512 + lane * 8;
    __bf16* ldsA1 = ldsA0 + 2048;
    __bf16* ldsB0 = sB + wv * 512 + lane * 8;
    __bf16* ldsB1 = ldsB0 + 2048;
    const __bf16* aBase = sA + (wr * 64) * 32;
    const __bf16* bBase = sB + (wc * 64) * 32;

    for (int k0 = 0; k0 < K; k0 += 32) {
        __syncthreads();                 // prior-iteration LDS reads done
        async_cp16(A + (long)r0 * as + k0 + koff,        ldsA0);
        async_cp16(A + (long)(r0 + 64) * as + k0 + koff, ldsA1);
        async_cp16(B + (long)r0 * bs + k0 + koff,        ldsB0);
        async_cp16(B + (long)(r0 + 64) * bs + k0 + koff, ldsB1);
        __syncthreads();                 // vmcnt drained at barrier -> data visible
        v8bf a[4], bf[4];
#pragma unroll
        for (int i = 0; i < 4; ++i)
            a[i] = *(const v8bf*)(aBase + (i * 16 + lq) * 32 + quad * 8);
#pragma unroll
        for (int j = 0; j < 4; ++j)
            bf[j] = *(const v8bf*)(bBase + (j * 16 + lq) * 32 + quad * 8);
#pragma unroll
        for (int i = 0; i < 4; ++i)
#pragma unroll
            for (int j = 0; j < 4; ++j)
                acc[i][j] = __builtin_amdgcn_mfma_f32_16x16x32_bf16(a[i], bf[j], acc[i][j], 0, 0, 0);
    }
}

// ---------------------------------------------------------------------------
// 256x256 GEMM core (round-5 schedule, best measured 68.6us on qkv).
//   Stage: ph1/2 -> T{k+1}.A halves (nxt buf); ph3/4 -> T{k+2}.B halves (cur).
//   Boundary vmcnt(4). Swizzle byte^=((row&7)<<4) src-side + ds_read-side.
//   No mid-phase drain: each phase's ds_reads are consumed by its own MFMAs
//   (compiler lgkm waits), trailing reads drain under MFMA.
// ---------------------------------------------------------------------------
__device__ __forceinline__ void gemm256_core(const bf16* __restrict__ A, long lda,
                                             const bf16* __restrict__ B, long ldb,
                                             int K, v4f acc[8][4], char* sLds) {
    const int t = threadIdx.x;
    const int lane = t & 63, wv = t >> 6;
    const int wm = wv >> 2, wn = wv & 3;
    const int lq = lane & 15, quad = lane >> 4;
    const int xsw = (lq & 7) << 4;
    const int kq0 = ((quad << 4)) ^ xsw;
    const int kq1 = (64 | (quad << 4)) ^ xsw;
    const int aRow0 = (wm * 128 + lq) << 7;
    const int bRow0 = (wn * 64 + lq) << 7;
    const int NT = K >> 6;

    auto STAGE = [&](const bf16* mb, long ld, int ldsbyte, int ktile, int h) {
#pragma unroll
        for (int s = 0; s < 2; ++s) {
            int L = (s << 13) + (t << 4);
            int row = L >> 7;
            int kb = (L & 127) ^ ((row & 7) << 4);
            const char* g = (const char*)(mb + (long)(h * 128 + row) * ld + (long)ktile * 64);
            async_cp16((const bf16*)(g + kb),
                       (__bf16*)(sLds + ldsbyte + (h << 14) + L));
        }
    };

    STAGE(B, ldb, 32768, 0, 0);
    STAGE(B, ldb, 32768, 0, 1);
    STAGE(A, lda, 0,     0, 0);
    STAGE(A, lda, 0,     0, 1);
    if (NT > 1) {
        STAGE(B, ldb, 65536 + 32768, 1, 0);
        STAGE(B, ldb, 65536 + 32768, 1, 1);
        asm volatile("s_waitcnt vmcnt(4)" ::: "memory");
    } else {
        asm volatile("s_waitcnt vmcnt(0)" ::: "memory");
    }
    __builtin_amdgcn_s_barrier();
    asm volatile("" ::: "memory");

    for (int kt = 0; kt < NT; ++kt) {
        const int cb = (kt & 1) << 16;
        const int nb = cb ^ 65536;
        const int bufA = cb, bufB = cb | 32768;
        v8bf a[4][2], b0[2][2], b1[2][2];

        // ---- phase 1: read A-quad0 + B-quad0; stage T{k+1}.A0; MFMA C(m0,n0)
#pragma unroll
        for (int ii = 0; ii < 4; ++ii) {
            a[ii][0] = *(const v8bf*)(sLds + bufA + aRow0 + ((ii * 16) << 7) + kq0);
            a[ii][1] = *(const v8bf*)(sLds + bufA + aRow0 + ((ii * 16) << 7) + kq1);
        }
#pragma unroll
        for (int jj = 0; jj < 2; ++jj) {
            b0[jj][0] = *(const v8bf*)(sLds + bufB + bRow0 + ((jj * 16) << 7) + kq0);
            b0[jj][1] = *(const v8bf*)(sLds + bufB + bRow0 + ((jj * 16) << 7) + kq1);
        }
        if (kt + 1 < NT) STAGE(A, lda, nb, kt + 1, 0);
        __builtin_amdgcn_s_setprio(1);
#pragma unroll
        for (int ii = 0; ii < 4; ++ii)
#pragma unroll
            for (int jj = 0; jj < 2; ++jj) {
                acc[ii][jj] = __builtin_amdgcn_mfma_f32_16x16x32_bf16(a[ii][0], b0[jj][0], acc[ii][jj], 0, 0, 0);
                acc[ii][jj] = __builtin_amdgcn_mfma_f32_16x16x32_bf16(a[ii][1], b0[jj][1], acc[ii][jj], 0, 0, 0);
            }
        __builtin_amdgcn_s_setprio(0);
        __builtin_amdgcn_s_barrier();
        asm volatile("" ::: "memory");

        // ---- phase 2: read B-quad1; stage T{k+1}.A1; MFMA C(m0,n1), reuse a
#pragma unroll
        for (int jj = 0; jj < 2; ++jj) {
            b1[jj][0] = *(const v8bf*)(sLds + bufB + bRow0 + ((32 + jj * 16) << 7) + kq0);
            b1[jj][1] = *(const v8bf*)(sLds + bufB + bRow0 + ((32 + jj * 16) << 7) + kq1);
        }
        if (kt + 1 < NT) STAGE(A, lda, nb, kt + 1, 1);
        __builtin_amdgcn_s_setprio(1);
#pragma unroll
        for (int ii = 0; ii < 4; ++ii)
#pragma unroll
            for (int jj = 0; jj < 2; ++jj) {
                acc[ii][2 + jj] = __builtin_amdgcn_mfma_f32_16x16x32_bf16(a[ii][0], b1[jj][0], acc[ii][2 + jj], 0, 0, 0);
                acc[ii][2 + jj] = __builtin_amdgcn_mfma_f32_16x16x32_bf16(a[ii][1], b1[jj][1], acc[ii][2 + jj], 0, 0, 0);
            }
        __builtin_amdgcn_s_setprio(0);
        __builtin_amdgcn_s_barrier();
        asm volatile("" ::: "memory");

        // ---- phase 3: read A-quad1; stage T{k+2}.B0 (cur bufB); MFMA C(m1,n1)
#pragma unroll
        for (int ii = 0; ii < 4; ++ii) {
            a[ii][0] = *(const v8bf*)(sLds + bufA + aRow0 + ((64 + ii * 16) << 7) + kq0);
            a[ii][1] = *(const v8bf*)(sLds + bufA + aRow0 + ((64 + ii * 16) << 7) + kq1);
        }
        if (kt + 2 < NT) STAGE(B, ldb, bufB, kt + 2, 0);
        __builtin_amdgcn_s_setprio(1);
#pragma unroll
        for (int ii = 0; ii < 4; ++ii)
#pragma unroll
            for (int jj = 0; jj < 2; ++jj) {
                acc[4 + ii][2 + jj] = __builtin_amdgcn_mfma_f32_16x16x32_bf16(a[ii][0], b1[jj][0], acc[4 + ii][2 + jj], 0, 0, 0);
                acc[4 + ii][2 + jj] = __builtin_amdgcn_mfma_f32_16x16x32_bf16(a[ii][1], b1[jj][1], acc[4 + ii][2 + jj], 0, 0, 0);
            }
        __builtin_amdgcn_s_setprio(0);
        __builtin_amdgcn_s_barrier();
        asm volatile("" ::: "memory");

        // ---- phase 4: stage T{k+2}.B1; MFMA C(m1,n0), reuse a + b0 ----
        if (kt + 2 < NT) STAGE(B, ldb, bufB, kt + 2, 1);
        __builtin_amdgcn_s_setprio(1);
#pragma unroll
        for (int ii = 0; ii < 4; ++ii)
#pragma unroll
            for (int jj = 0; jj < 2; ++jj) {
                acc[4 + ii][jj] = __builtin_amdgcn_mfma_f32_16x16x32_bf16(a[ii][0], b0[jj][0], acc[4 + ii][jj], 0, 0, 0);
                acc[4 + ii][jj] = __builtin_amdgcn_mfma_f32_16x16x32_bf16(a[ii][1], b0[jj][1], acc[4 + ii][jj], 0, 0, 0);
            }
        __builtin_amdgcn_s_setprio(0);
        if (kt + 2 < NT) asm volatile("s_waitcnt vmcnt(4)" ::: "memory");
        else             asm volatile("s_waitcnt vmcnt(0)" ::: "memory");
        __builtin_amdgcn_s_barrier();
        asm volatile("" ::: "memory");
    }
}

// ---------------------------------------------------------------------------
// QKV GEMM (swapped): D[n][o] = sum_k hnT[n][k] * Wqkv[o][k]  (+bias)
// q,k (o<1024) -> qkbuf[b][o][n]; v (o>=1024) -> vT[b][n][e].
// 256x256 tiles: grid (16 n-tiles, 6 o-tiles, 8 b), 512 threads.
// ---------------------------------------------------------------------------
__global__ __launch_bounds__(512, 2) void qkv_gemm_kernel(const bf16* __restrict__ hnT,
                                                          const bf16* __restrict__ qkv_wb,
                                                          const float* __restrict__ qkv_b,
                                                          bf16* __restrict__ qkbuf,
                                                          bf16* __restrict__ vT) {
    __shared__ __align__(16) char sLds[131072];
    int n0 = blockIdx.x * 256, o0 = blockIdx.y * 256, b = blockIdx.z;
    v4f acc[8][4] = {};
    gemm256_core(hnT + ((long)b * NSP + n0) * CCH, CCH,
                 qkv_wb + (long)o0 * CCH, CCH, CCH, acc, sLds);
    int t = threadIdx.x, lane = t & 63, wv = t >> 6, wm = wv >> 2, wn = wv & 3;
    int lq = lane & 15, quad = lane >> 4;
    if (o0 < 1024) {
#pragma unroll
        for (int j = 0; j < 4; ++j) {
            int o = o0 + wn * 64 + j * 16 + lq;
            float bias = qkv_b[o];
#pragma unroll
            for (int i = 0; i < 8; ++i) {
                int n = n0 + wm * 128 + i * 16 + quad * 4;
                v4f v = acc[i][j];
                bf16x4 ov = { f2b(v[0] + bias), f2b(v[1] + bias),
                              f2b(v[2] + bias), f2b(v[3] + bias) };
                *(bf16x4*)&qkbuf[((long)b * 1024 + o) * NSP + n] = ov;
            }
        }
    } else {
#pragma unroll
        for (int j = 0; j < 4; ++j) {
            int e = o0 - 1024 + wn * 64 + j * 16 + lq;
            float bias = qkv_b[1024 + e];
#pragma unroll
            for (int i = 0; i < 8; ++i) {
                int n = n0 + wm * 128 + i * 16 + quad * 4;
                v4f v = acc[i][j];
#pragma unroll
                for (int r = 0; r < 4; ++r)
                    vT[((long)b * NSP + n + r) * CCH + e] = f2b(v[r] + bias);
            }
        }
    }
}

// ---------------------------------------------------------------------------
// QK^T split-K: P_part[s][bh][d][e] = sum_{n in split} q[d][n]*k[e][n]
// grid (8 splits, 32 bh) -- old core (N panel = 128 only)
// ---------------------------------------------------------------------------
__global__ __launch_bounds__(256) void qk_gemm_kernel(const bf16* __restrict__ qkbuf,
                                                      float* __restrict__ P_part) {
    __shared__ __align__(16) __bf16 sA[128 * 32];
    __shared__ __align__(16) __bf16 sB[128 * 32];
    int s = blockIdx.x, bh = blockIdx.y;
    int b = bh >> 2, h = bh & 3;
    const bf16* q  = qkbuf + ((long)b * 1024 + h * 128) * NSP + s * 512;
    const bf16* kk = qkbuf + ((long)b * 1024 + 512 + h * 128) * NSP + s * 512;
    v4f acc[4][4] = {};
    gemm_core(q, NSP, kk, NSP, 512, acc, sA, sB);
    float* Pp = P_part + ((long)s * 32 + bh) * 16384;
    int t = threadIdx.x, lane = t & 63, wv = t >> 6, wr = wv >> 1, wc = wv & 1;
    int lq = lane & 15, quad = lane >> 4;
#pragma unroll
    for (int j = 0; j < 4; ++j) {
        int e = wc * 64 + j * 16 + lq;
#pragma unroll
        for (int i = 0; i < 4; ++i) {
            int d = wr * 64 + i * 16 + quad * 4;
            v4f v = acc[i][j];
#pragma unroll
            for (int r = 0; r < 4; ++r) Pp[(long)(d + r) * 128 + e] = v[r];
        }
    }
}

// ---------------------------------------------------------------------------
// Softmax: sum 8 partials, scale by d^-0.5, softmax over e, emit bf16 P.
// ---------------------------------------------------------------------------
__global__ __launch_bounds__(128) void softmax_kernel(const float* __restrict__ P_part,
                                                      bf16* __restrict__ Pb) {
    int row = blockIdx.x;
    int bh = row >> 7, d = row & 127;
    int t = threadIdx.x;
    float v = 0.f;
#pragma unroll
    for (int s = 0; s < 8; ++s)
        v += P_part[((long)s * 32 + bh) * 16384 + (long)d * 128 + t];
    v *= 0.08838834764831845f;
    float m = v;
    for (int off = 32; off > 0; off >>= 1) m = fmaxf(m, __shfl_down(m, off));
    __shared__ float sm[2];
    if ((t & 63) == 0) sm[t >> 6] = m;
    __syncthreads();
    m = fmaxf(sm[0], sm[1]);
    float e = __expf(v - m);
    float ssum = e;
    for (int off = 32; off > 0; off >>= 1) ssum += __shfl_down(ssum, off);
    __shared__ float ss[2];
    if ((t & 63) == 0) ss[t >> 6] = ssum;
    __syncthreads();
    ssum = ss[0] + ss[1];
    Pb[(long)row * 128 + t] = f2b(e / ssum);
}

// ---------------------------------------------------------------------------
// PV (v1, old core — best measured): attT[b][n][h*128+d] = sum_e P[d][e]*vT[n][e]
// grid (32 n-tiles, 32 bh)
// ---------------------------------------------------------------------------
__global__ __launch_bounds__(256) void pv_gemm_kernel(const bf16* __restrict__ Pb,
                                                      const bf16* __restrict__ vT,
                                                      bf16* __restrict__ attT) {
    __shared__ __align__(16) __bf16 sA[128 * 32];
    __shared__ __align__(16) __bf16 sB[128 * 32];
    int n0 = blockIdx.x * 128, bh = blockIdx.y;
    int b = bh >> 2, h = bh & 3;
    v4f acc[4][4] = {};
    gemm_core(Pb + (long)bh * 16384, 128,
              vT + ((long)b * NSP + n0) * CCH + h * 128, CCH, 128, acc, sA, sB);
    int t = threadIdx.x, lane = t & 63, wv = t >> 6, wr = wv >> 1, wc = wv & 1;
    int lq = lane & 15, quad = lane >> 4;
#pragma unroll
    for (int j = 0; j < 4; ++j) {
        int n = n0 + wc * 64 + j * 16 + lq;
#pragma unroll
        for (int i = 0; i < 4; ++i) {
            int d = wr * 64 + i * 16 + quad * 4;
            v4f v = acc[i][j];
            bf16x4 ov = { f2b(v[0]), f2b(v[1]), f2b(v[2]), f2b(v[3]) };
            *(bf16x4*)&attT[((long)b * NSP + n) * CCH + h * 128 + d] = ov;
        }
    }
}

// ---------------------------------------------------------------------------
// Proj (swapped): out[b][c][n] = sum_k attT[n][k]*Wp[c][k] + bias[c] + x
// 256x256 tiles: grid (16 n-tiles, 2 c-tiles, 8 b), 512 threads.
// ---------------------------------------------------------------------------
__global__ __launch_bounds__(512, 2) void proj_gemm_kernel(const bf16* __restrict__ attT,
                                                           const bf16* __restrict__ proj_wb,
                                                           const float* __restrict__ proj_b,
                                                           const float* __restrict__ x,
                                                           float* __restrict__ out) {
    __shared__ __align__(16) char sLds[131072];
    int n0 = blockIdx.x * 256, c0 = blockIdx.y * 256, b = blockIdx.z;
    v4f acc[8][4] = {};
    gemm256_core(attT + ((long)b * NSP + n0) * CCH, CCH,
                 proj_wb + (long)c0 * CCH, CCH, CCH, acc, sLds);
    int t = threadIdx.x, lane = t & 63, wv = t >> 6, wm = wv >> 2, wn = wv & 3;
    int lq = lane & 15, quad = lane >> 4;
#pragma unroll
    for (int j = 0; j < 4; ++j) {
        int c = c0 + wn * 64 + j * 16 + lq;
        float bias = proj_b[c];
#pragma unroll
        for (int i = 0; i < 8; ++i) {
            int n = n0 + wm * 128 + i * 16 + quad * 4;
            long idx = ((long)b * CCH + c) * NSP + n;
            float4 r = *(const float4*)&x[idx];
            v4f v = acc[i][j];
            float4 ov = { v[0] + bias + r.x, v[1] + bias + r.y,
                          v[2] + bias + r.z, v[3] + bias + r.w };
            *(float4*)&out[idx] = ov;
        }
    }
}

// ---------------------------------------------------------------------------
extern "C" void kernel_launch(void* const* d_in, const int* in_sizes, int n_in,
                              void* d_out, int out_size, void* d_ws, size_t ws_size,
                              hipStream_t stream) {
    const float* x      = (const float*)d_in[0];
    const float* gn_w   = (const float*)d_in[1];
    const float* gn_b   = (const float*)d_in[2];
    const float* qkv_w  = (const float*)d_in[3];
    const float* qkv_b  = (const float*)d_in[4];
    const float* proj_w = (const float*)d_in[5];
    const float* proj_b = (const float*)d_in[6];
    float* out = (float*)d_out;

    char* ws = (char*)d_ws;
    // region0 (33.5 MB) reused over time: hnT -> P_part -> attT
    bf16*  hnT    = (bf16*)ws;
    float* P_part = (float*)ws;                    // 8*32*128*128 fp32 = 16.8 MB
    bf16*  attT   = (bf16*)ws;
    bf16*  qkbuf  = (bf16*)(ws + 33554432);        // [b][1024][4096] bf16 = 67.1 MB
    bf16*  vT     = (bf16*)(ws + 100663296);       // [b][4096][512]  bf16 = 33.5 MB
    bf16*  Pb     = (bf16*)(ws + 134217728);       // 32*128*128 bf16 = 1 MB
    float* stats  = (float*)(ws + 135266304);      // 256*2 fp32
    bf16*  qkv_wb = (bf16*)(ws + 135270400);       // 1536*512 bf16 = 1.5 MB
    bf16*  proj_wb= (bf16*)(ws + 136843264);       // 512*512 bf16 = 0.5 MB

    wconv2_kernel<<<1024, 256, 0, stream>>>(qkv_w, proj_w, qkv_wb, proj_wb);
    gn_stats_kernel<<<256, 256, 0, stream>>>(x, stats);
    gn_norm_t_kernel<<<dim3(64, 8, 8), 256, 0, stream>>>(x, gn_w, gn_b, stats, hnT);
    qkv_gemm_kernel<<<dim3(16, 6, 8), 512, 0, stream>>>(hnT, qkv_wb, qkv_b, qkbuf, vT);
    qk_gemm_kernel<<<dim3(8, 32), 256, 0, stream>>>(qkbuf, P_part);
    softmax_kernel<<<4096, 128, 0, stream>>>(P_part, Pb);
    pv_gemm_kernel<<<dim3(32, 32), 256, 0, stream>>>(Pb, vT, attT);
    proj_gemm_kernel<<<dim3(16, 2, 8), 512, 0, stream>>>(attT, proj_wb, proj_b, x, out);
}

// Round 9
// 286.239 us; speedup vs baseline: 1.2237x; 1.0542x over previous
//
#include <hip/hip_runtime.h>
#include <hip/hip_bf16.h>

typedef __hip_bfloat16 bf16;
typedef __bf16 v8bf __attribute__((ext_vector_type(8)));
typedef float  v4f  __attribute__((ext_vector_type(4)));

struct __align__(8) bf16x4 { bf16 x, y, z, w; };

__device__ __forceinline__ bf16 f2b(float v) { return __float2bfloat16(v); }

// B=8, C=512, H=W=64 -> N=4096, HEADS=4, d=128, GROUPS=32
#define NSP 4096
#define CCH 512

// Async 16B global -> LDS (gfx950 direct-to-LDS, wave-uniform base + lane*16).
__device__ __forceinline__ void async_cp16(const bf16* g, __bf16* l) {
    __builtin_amdgcn_global_load_lds(
        (const __attribute__((address_space(1))) unsigned int*)(unsigned long long)g,
        (__attribute__((address_space(3))) unsigned int*)(unsigned int)(unsigned long long)l,
        16, 0, 0);
}

// ---------------------------------------------------------------------------
// Weight fp32 -> bf16 conversion, both weight tensors in one launch.
// ---------------------------------------------------------------------------
__global__ __launch_bounds__(256) void wconv2_kernel(const float* __restrict__ qw,
                                                     const float* __restrict__ pw,
                                                     bf16* __restrict__ qd,
                                                     bf16* __restrict__ pd) {
    int i = blockIdx.x * 256 + threadIdx.x;
    if (i < 196608) {
        float4 v = ((const float4*)qw)[i];
        bf16x4 o = { f2b(v.x), f2b(v.y), f2b(v.z), f2b(v.w) };
        ((bf16x4*)qd)[i] = o;
    } else {
        int j = i - 196608;
        float4 v = ((const float4*)pw)[j];
        bf16x4 o = { f2b(v.x), f2b(v.y), f2b(v.z), f2b(v.w) };
        ((bf16x4*)pd)[j] = o;
    }
}

// ---------------------------------------------------------------------------
// GN pass 1: per-(b,group) mean/rstd. 256 blocks x 1024 threads (16 waves).
// ---------------------------------------------------------------------------
__global__ __launch_bounds__(1024) void gn_stats_kernel(const float* __restrict__ x,
                                                        float* __restrict__ stats) {
    int blk = blockIdx.x;
    int b = blk >> 5, g = blk & 31;
    size_t base = ((size_t)(b * CCH + g * 16)) * NSP;     // 65536 floats
    const float4* xp4 = (const float4*)(x + base);
    int t = threadIdx.x;
    float s = 0.f, s2 = 0.f;
    for (int i = t; i < 16384; i += 1024) {
        float4 v = xp4[i];
        s  += v.x + v.y + v.z + v.w;
        s2 += v.x * v.x + v.y * v.y + v.z * v.z + v.w * v.w;
    }
    for (int off = 32; off > 0; off >>= 1) {
        s  += __shfl_down(s, off);
        s2 += __shfl_down(s2, off);
    }
    __shared__ float red[32];
    int wid = t >> 6, lid = t & 63;
    if (lid == 0) { red[wid] = s; red[wid + 16] = s2; }
    __syncthreads();
    if (t == 0) {
        float ts = 0.f, ts2 = 0.f;
#pragma unroll
        for (int w = 0; w < 16; ++w) { ts += red[w]; ts2 += red[w + 16]; }
        float mean = ts * (1.f / 65536.f);
        float var  = ts2 * (1.f / 65536.f) - mean * mean;
        stats[blk * 2]     = mean;
        stats[blk * 2 + 1] = rsqrtf(var + 1e-5f);
    }
}

// ---------------------------------------------------------------------------
// GN pass 2: normalize + transpose to n-major hnT[b][n][c] (bf16).
// ---------------------------------------------------------------------------
__global__ __launch_bounds__(256) void gn_norm_t_kernel(const float* __restrict__ x,
                                                        const float* __restrict__ gw,
                                                        const float* __restrict__ gb,
                                                        const float* __restrict__ stats,
                                                        bf16* __restrict__ hnT) {
    __shared__ float sT[64][65];
    int n0 = blockIdx.x * 64, c0 = blockIdx.y * 64, b = blockIdx.z;
    int t = threadIdx.x;
    int cl = t >> 4, nl4 = (t & 15) << 2;
#pragma unroll
    for (int it = 0; it < 4; ++it) {
        int crow = cl + it * 16;
        int c = c0 + crow;
        int bg = b * 32 + (c >> 4);
        float mean = stats[bg * 2], rstd = stats[bg * 2 + 1];
        float wsc = gw[c] * rstd;
        float bb  = gb[c] - mean * wsc;
        float4 v = *(const float4*)&x[((long)b * CCH + c) * NSP + n0 + nl4];
        sT[crow][nl4 + 0] = v.x * wsc + bb;
        sT[crow][nl4 + 1] = v.y * wsc + bb;
        sT[crow][nl4 + 2] = v.z * wsc + bb;
        sT[crow][nl4 + 3] = v.w * wsc + bb;
    }
    __syncthreads();
    int nl = t >> 4, cl4 = (t & 15) << 2;
#pragma unroll
    for (int it = 0; it < 4; ++it) {
        int nrow = nl + it * 16;
        bf16x4 ov = { f2b(sT[cl4 + 0][nrow]), f2b(sT[cl4 + 1][nrow]),
                      f2b(sT[cl4 + 2][nrow]), f2b(sT[cl4 + 3][nrow]) };
        *(bf16x4*)&hnT[((long)b * NSP + n0 + nrow) * CCH + c0 + cl4] = ov;
    }
}

// ---------------------------------------------------------------------------
// OLD MFMA GEMM core (m97 structure): used by QK^T and PV.
// 128x128 tile, BK=32, 256 threads (4 waves 2x2).
// ---------------------------------------------------------------------------
__device__ __forceinline__ void gemm_core(const bf16* __restrict__ A, long as,
                                          const bf16* __restrict__ B, long bs,
                                          int K, v4f acc[4][4],
                                          __bf16* sA, __bf16* sB) {
    int t = threadIdx.x;
    int lane = t & 63, wv = t >> 6;
    int wr = wv >> 1, wc = wv & 1;
    int lq = lane & 15, quad = lane >> 4;
    int r0 = wv * 16 + (lane >> 2);      // staging row, issue 0
    int koff = (lane & 3) * 8;           // staging k offset (elements)
    __bf16* ldsA0 = sA + wv * 512 + lane * 8;
    __bf16* ldsA1 = ldsA0 + 2048;
    __bf16* ldsB0 = sB + wv * 512 + lane * 8;
    __bf16* ldsB1 = ldsB0 + 2048;
    const __bf16* aBase = sA + (wr * 64) * 32;
    const __bf16* bBase = sB + (wc * 64) * 32;

    for (int k0 = 0; k0 < K; k0 += 32) {
        __syncthreads();                 // prior-iteration LDS reads done
        async_cp16(A + (long)r0 * as + k0 + koff,        ldsA0);
        async_cp16(A + (long)(r0 + 64) * as + k0 + koff, ldsA1);
        async_cp16(B + (long)r0 * bs + k0 + koff,        ldsB0);
        async_cp16(B + (long)(r0 + 64) * bs + k0 + koff, ldsB1);
        __syncthreads();                 // vmcnt drained at barrier -> data visible
        v8bf a[4], bf[4];
#pragma unroll
        for (int i = 0; i < 4; ++i)
            a[i] = *(const v8bf*)(aBase + (i * 16 + lq) * 32 + quad * 8);
#pragma unroll
        for (int j = 0; j < 4; ++j)
            bf[j] = *(const v8bf*)(bBase + (j * 16 + lq) * 32 + quad * 8);
#pragma unroll
        for (int i = 0; i < 4; ++i)
#pragma unroll
            for (int j = 0; j < 4; ++j)
                acc[i][j] = __builtin_amdgcn_mfma_f32_16x16x32_bf16(a[i], bf[j], acc[i][j], 0, 0, 0);
    }
}

// ---------------------------------------------------------------------------
// 256x256 GEMM core, m201-style DOUBLE-BARRIER phases (this round):
//   phase = { ds_read quadrant; STAGE; barrier; lgkmcnt(0); setprio(1);
//             MFMA x16; setprio(0); barrier }   -- NO sched_barrier(0).
//   All 8 waves' ds_reads batch-drain while waves arrive at barrier-1, so
//   lgkmcnt(0) is nearly free and the MFMA cluster runs clean at prio 1.
//   Stage: ph1/2 -> T{k+1}.A halves (nxt buf); ph3/4 -> T{k+2}.B halves (cur).
//   Boundary vmcnt(4). Swizzle byte^=((row&7)<<4) src-side + ds_read-side.
// ---------------------------------------------------------------------------
__device__ __forceinline__ void gemm256_core(const bf16* __restrict__ A, long lda,
                                             const bf16* __restrict__ B, long ldb,
                                             int K, v4f acc[8][4], char* sLds) {
    const int t = threadIdx.x;
    const int lane = t & 63, wv = t >> 6;
    const int wm = wv >> 2, wn = wv & 3;
    const int lq = lane & 15, quad = lane >> 4;
    const int xsw = (lq & 7) << 4;
    const int kq0 = ((quad << 4)) ^ xsw;
    const int kq1 = (64 | (quad << 4)) ^ xsw;
    const int aRow0 = (wm * 128 + lq) << 7;
    const int bRow0 = (wn * 64 + lq) << 7;
    const int NT = K >> 6;

    auto STAGE = [&](const bf16* mb, long ld, int ldsbyte, int ktile, int h) {
#pragma unroll
        for (int s = 0; s < 2; ++s) {
            int L = (s << 13) + (t << 4);
            int row = L >> 7;
            int kb = (L & 127) ^ ((row & 7) << 4);
            const char* g = (const char*)(mb + (long)(h * 128 + row) * ld + (long)ktile * 64);
            async_cp16((const bf16*)(g + kb),
                       (__bf16*)(sLds + ldsbyte + (h << 14) + L));
        }
    };

    STAGE(B, ldb, 32768, 0, 0);
    STAGE(B, ldb, 32768, 0, 1);
    STAGE(A, lda, 0,     0, 0);
    STAGE(A, lda, 0,     0, 1);
    if (NT > 1) {
        STAGE(B, ldb, 65536 + 32768, 1, 0);
        STAGE(B, ldb, 65536 + 32768, 1, 1);
        asm volatile("s_waitcnt vmcnt(4)" ::: "memory");
    } else {
        asm volatile("s_waitcnt vmcnt(0)" ::: "memory");
    }
    __builtin_amdgcn_s_barrier();
    asm volatile("" ::: "memory");

    for (int kt = 0; kt < NT; ++kt) {
        const int cb = (kt & 1) << 16;
        const int nb = cb ^ 65536;
        const int bufA = cb, bufB = cb | 32768;
        v8bf a[4][2], b0[2][2], b1[2][2];

        // ---- phase 1: read A-quad0 + B-quad0; stage T{k+1}.A0 ----
#pragma unroll
        for (int ii = 0; ii < 4; ++ii) {
            a[ii][0] = *(const v8bf*)(sLds + bufA + aRow0 + ((ii * 16) << 7) + kq0);
            a[ii][1] = *(const v8bf*)(sLds + bufA + aRow0 + ((ii * 16) << 7) + kq1);
        }
#pragma unroll
        for (int jj = 0; jj < 2; ++jj) {
            b0[jj][0] = *(const v8bf*)(sLds + bufB + bRow0 + ((jj * 16) << 7) + kq0);
            b0[jj][1] = *(const v8bf*)(sLds + bufB + bRow0 + ((jj * 16) << 7) + kq1);
        }
        if (kt + 1 < NT) STAGE(A, lda, nb, kt + 1, 0);
        __builtin_amdgcn_s_barrier();
        asm volatile("s_waitcnt lgkmcnt(0)" ::: "memory");
        __builtin_amdgcn_s_setprio(1);
#pragma unroll
        for (int ii = 0; ii < 4; ++ii)
#pragma unroll
            for (int jj = 0; jj < 2; ++jj) {
                acc[ii][jj] = __builtin_amdgcn_mfma_f32_16x16x32_bf16(a[ii][0], b0[jj][0], acc[ii][jj], 0, 0, 0);
                acc[ii][jj] = __builtin_amdgcn_mfma_f32_16x16x32_bf16(a[ii][1], b0[jj][1], acc[ii][jj], 0, 0, 0);
            }
        __builtin_amdgcn_s_setprio(0);
        __builtin_amdgcn_s_barrier();
        asm volatile("" ::: "memory");

        // ---- phase 2: read B-quad1; stage T{k+1}.A1; MFMA reuse a ----
#pragma unroll
        for (int jj = 0; jj < 2; ++jj) {
            b1[jj][0] = *(const v8bf*)(sLds + bufB + bRow0 + ((32 + jj * 16) << 7) + kq0);
            b1[jj][1] = *(const v8bf*)(sLds + bufB + bRow0 + ((32 + jj * 16) << 7) + kq1);
        }
        if (kt + 1 < NT) STAGE(A, lda, nb, kt + 1, 1);
        __builtin_amdgcn_s_barrier();
        asm volatile("s_waitcnt lgkmcnt(0)" ::: "memory");
        __builtin_amdgcn_s_setprio(1);
#pragma unroll
        for (int ii = 0; ii < 4; ++ii)
#pragma unroll
            for (int jj = 0; jj < 2; ++jj) {
                acc[ii][2 + jj] = __builtin_amdgcn_mfma_f32_16x16x32_bf16(a[ii][0], b1[jj][0], acc[ii][2 + jj], 0, 0, 0);
                acc[ii][2 + jj] = __builtin_amdgcn_mfma_f32_16x16x32_bf16(a[ii][1], b1[jj][1], acc[ii][2 + jj], 0, 0, 0);
            }
        __builtin_amdgcn_s_setprio(0);
        __builtin_amdgcn_s_barrier();
        asm volatile("" ::: "memory");

        // ---- phase 3: read A-quad1; stage T{k+2}.B0 (cur bufB); MFMA reuse b1
#pragma unroll
        for (int ii = 0; ii < 4; ++ii) {
            a[ii][0] = *(const v8bf*)(sLds + bufA + aRow0 + ((64 + ii * 16) << 7) + kq0);
            a[ii][1] = *(const v8bf*)(sLds + bufA + aRow0 + ((64 + ii * 16) << 7) + kq1);
        }
        if (kt + 2 < NT) STAGE(B, ldb, bufB, kt + 2, 0);
        __builtin_amdgcn_s_barrier();
        asm volatile("s_waitcnt lgkmcnt(0)" ::: "memory");
        __builtin_amdgcn_s_setprio(1);
#pragma unroll
        for (int ii = 0; ii < 4; ++ii)
#pragma unroll
            for (int jj = 0; jj < 2; ++jj) {
                acc[4 + ii][2 + jj] = __builtin_amdgcn_mfma_f32_16x16x32_bf16(a[ii][0], b1[jj][0], acc[4 + ii][2 + jj], 0, 0, 0);
                acc[4 + ii][2 + jj] = __builtin_amdgcn_mfma_f32_16x16x32_bf16(a[ii][1], b1[jj][1], acc[4 + ii][2 + jj], 0, 0, 0);
            }
        __builtin_amdgcn_s_setprio(0);
        __builtin_amdgcn_s_barrier();
        asm volatile("" ::: "memory");

        // ---- phase 4: stage T{k+2}.B1; MFMA reuse a + b0 ----
        if (kt + 2 < NT) STAGE(B, ldb, bufB, kt + 2, 1);
        __builtin_amdgcn_s_barrier();
        __builtin_amdgcn_s_setprio(1);
#pragma unroll
        for (int ii = 0; ii < 4; ++ii)
#pragma unroll
            for (int jj = 0; jj < 2; ++jj) {
                acc[4 + ii][jj] = __builtin_amdgcn_mfma_f32_16x16x32_bf16(a[ii][0], b0[jj][0], acc[4 + ii][jj], 0, 0, 0);
                acc[4 + ii][jj] = __builtin_amdgcn_mfma_f32_16x16x32_bf16(a[ii][1], b0[jj][1], acc[4 + ii][jj], 0, 0, 0);
            }
        __builtin_amdgcn_s_setprio(0);
        if (kt + 2 < NT) asm volatile("s_waitcnt vmcnt(4)" ::: "memory");
        else             asm volatile("s_waitcnt vmcnt(0)" ::: "memory");
        __builtin_amdgcn_s_barrier();
        asm volatile("" ::: "memory");
    }
}

// ---------------------------------------------------------------------------
// QKV GEMM (swapped): D[n][o] = sum_k hnT[n][k] * Wqkv[o][k]  (+bias)
// q,k (o<1024) -> qkbuf[b][o][n]; v (o>=1024) -> vT[b][n][e].
// 256x256 tiles: grid (16 n-tiles, 6 o-tiles, 8 b), 512 threads.
// ---------------------------------------------------------------------------
__global__ __launch_bounds__(512, 2) void qkv_gemm_kernel(const bf16* __restrict__ hnT,
                                                          const bf16* __restrict__ qkv_wb,
                                                          const float* __restrict__ qkv_b,
                                                          bf16* __restrict__ qkbuf,
                                                          bf16* __restrict__ vT) {
    __shared__ __align__(16) char sLds[131072];
    int n0 = blockIdx.x * 256, o0 = blockIdx.y * 256, b = blockIdx.z;
    v4f acc[8][4] = {};
    gemm256_core(hnT + ((long)b * NSP + n0) * CCH, CCH,
                 qkv_wb + (long)o0 * CCH, CCH, CCH, acc, sLds);
    int t = threadIdx.x, lane = t & 63, wv = t >> 6, wm = wv >> 2, wn = wv & 3;
    int lq = lane & 15, quad = lane >> 4;
    if (o0 < 1024) {
#pragma unroll
        for (int j = 0; j < 4; ++j) {
            int o = o0 + wn * 64 + j * 16 + lq;
            float bias = qkv_b[o];
#pragma unroll
            for (int i = 0; i < 8; ++i) {
                int n = n0 + wm * 128 + i * 16 + quad * 4;
                v4f v = acc[i][j];
                bf16x4 ov = { f2b(v[0] + bias), f2b(v[1] + bias),
                              f2b(v[2] + bias), f2b(v[3] + bias) };
                *(bf16x4*)&qkbuf[((long)b * 1024 + o) * NSP + n] = ov;
            }
        }
    } else {
#pragma unroll
        for (int j = 0; j < 4; ++j) {
            int e = o0 - 1024 + wn * 64 + j * 16 + lq;
            float bias = qkv_b[1024 + e];
#pragma unroll
            for (int i = 0; i < 8; ++i) {
                int n = n0 + wm * 128 + i * 16 + quad * 4;
                v4f v = acc[i][j];
#pragma unroll
                for (int r = 0; r < 4; ++r)
                    vT[((long)b * NSP + n + r) * CCH + e] = f2b(v[r] + bias);
            }
        }
    }
}

// ---------------------------------------------------------------------------
// QK^T split-K 16: P_part[s][bh][d][e] = sum_{n in split} q[d][n]*k[e][n]
// grid (16 splits, 32 bh), K=256 each -> 512 blocks = 2 blocks/CU.
// ---------------------------------------------------------------------------
__global__ __launch_bounds__(256) void qk_gemm_kernel(const bf16* __restrict__ qkbuf,
                                                      float* __restrict__ P_part) {
    __shared__ __align__(16) __bf16 sA[128 * 32];
    __shared__ __align__(16) __bf16 sB[128 * 32];
    int s = blockIdx.x, bh = blockIdx.y;
    int b = bh >> 2, h = bh & 3;
    const bf16* q  = qkbuf + ((long)b * 1024 + h * 128) * NSP + s * 256;
    const bf16* kk = qkbuf + ((long)b * 1024 + 512 + h * 128) * NSP + s * 256;
    v4f acc[4][4] = {};
    gemm_core(q, NSP, kk, NSP, 256, acc, sA, sB);
    float* Pp = P_part + ((long)s * 32 + bh) * 16384;
    int t = threadIdx.x, lane = t & 63, wv = t >> 6, wr = wv >> 1, wc = wv & 1;
    int lq = lane & 15, quad = lane >> 4;
#pragma unroll
    for (int j = 0; j < 4; ++j) {
        int e = wc * 64 + j * 16 + lq;
#pragma unroll
        for (int i = 0; i < 4; ++i) {
            int d = wr * 64 + i * 16 + quad * 4;
            v4f v = acc[i][j];
#pragma unroll
            for (int r = 0; r < 4; ++r) Pp[(long)(d + r) * 128 + e] = v[r];
        }
    }
}

// ---------------------------------------------------------------------------
// Softmax: sum 16 partials, scale by d^-0.5, softmax over e, emit bf16 P.
// ---------------------------------------------------------------------------
__global__ __launch_bounds__(128) void softmax_kernel(const float* __restrict__ P_part,
                                                      bf16* __restrict__ Pb) {
    int row = blockIdx.x;
    int bh = row >> 7, d = row & 127;
    int t = threadIdx.x;
    float v = 0.f;
#pragma unroll
    for (int s = 0; s < 16; ++s)
        v += P_part[((long)s * 32 + bh) * 16384 + (long)d * 128 + t];
    v *= 0.08838834764831845f;
    float m = v;
    for (int off = 32; off > 0; off >>= 1) m = fmaxf(m, __shfl_down(m, off));
    __shared__ float sm[2];
    if ((t & 63) == 0) sm[t >> 6] = m;
    __syncthreads();
    m = fmaxf(sm[0], sm[1]);
    float e = __expf(v - m);
    float ssum = e;
    for (int off = 32; off > 0; off >>= 1) ssum += __shfl_down(ssum, off);
    __shared__ float ss[2];
    if ((t & 63) == 0) ss[t >> 6] = ssum;
    __syncthreads();
    ssum = ss[0] + ss[1];
    Pb[(long)row * 128 + t] = f2b(e / ssum);
}

// ---------------------------------------------------------------------------
// PV (v1, old core — best measured): attT[b][n][h*128+d] = sum_e P[d][e]*vT[n][e]
// grid (32 n-tiles, 32 bh)
// ---------------------------------------------------------------------------
__global__ __launch_bounds__(256) void pv_gemm_kernel(const bf16* __restrict__ Pb,
                                                      const bf16* __restrict__ vT,
                                                      bf16* __restrict__ attT) {
    __shared__ __align__(16) __bf16 sA[128 * 32];
    __shared__ __align__(16) __bf16 sB[128 * 32];
    int n0 = blockIdx.x * 128, bh = blockIdx.y;
    int b = bh >> 2, h = bh & 3;
    v4f acc[4][4] = {};
    gemm_core(Pb + (long)bh * 16384, 128,
              vT + ((long)b * NSP + n0) * CCH + h * 128, CCH, 128, acc, sA, sB);
    int t = threadIdx.x, lane = t & 63, wv = t >> 6, wr = wv >> 1, wc = wv & 1;
    int lq = lane & 15, quad = lane >> 4;
#pragma unroll
    for (int j = 0; j < 4; ++j) {
        int n = n0 + wc * 64 + j * 16 + lq;
#pragma unroll
        for (int i = 0; i < 4; ++i) {
            int d = wr * 64 + i * 16 + quad * 4;
            v4f v = acc[i][j];
            bf16x4 ov = { f2b(v[0]), f2b(v[1]), f2b(v[2]), f2b(v[3]) };
            *(bf16x4*)&attT[((long)b * NSP + n) * CCH + h * 128 + d] = ov;
        }
    }
}

// ---------------------------------------------------------------------------
// Proj (swapped): out[b][c][n] = sum_k attT[n][k]*Wp[c][k] + bias[c] + x
// 256x256 tiles: grid (16 n-tiles, 2 c-tiles, 8 b), 512 threads.
// ---------------------------------------------------------------------------
__global__ __launch_bounds__(512, 2) void proj_gemm_kernel(const bf16* __restrict__ attT,
                                                           const bf16* __restrict__ proj_wb,
                                                           const float* __restrict__ proj_b,
                                                           const float* __restrict__ x,
                                                           float* __restrict__ out) {
    __shared__ __align__(16) char sLds[131072];
    int n0 = blockIdx.x * 256, c0 = blockIdx.y * 256, b = blockIdx.z;
    v4f acc[8][4] = {};
    gemm256_core(attT + ((long)b * NSP + n0) * CCH, CCH,
                 proj_wb + (long)c0 * CCH, CCH, CCH, acc, sLds);
    int t = threadIdx.x, lane = t & 63, wv = t >> 6, wm = wv >> 2, wn = wv & 3;
    int lq = lane & 15, quad = lane >> 4;
#pragma unroll
    for (int j = 0; j < 4; ++j) {
        int c = c0 + wn * 64 + j * 16 + lq;
        float bias = proj_b[c];
#pragma unroll
        for (int i = 0; i < 8; ++i) {
            int n = n0 + wm * 128 + i * 16 + quad * 4;
            long idx = ((long)b * CCH + c) * NSP + n;
            float4 r = *(const float4*)&x[idx];
            v4f v = acc[i][j];
            float4 ov = { v[0] + bias + r.x, v[1] + bias + r.y,
                          v[2] + bias + r.z, v[3] + bias + r.w };
            *(float4*)&out[idx] = ov;
        }
    }
}

// ---------------------------------------------------------------------------
extern "C" void kernel_launch(void* const* d_in, const int* in_sizes, int n_in,
                              void* d_out, int out_size, void* d_ws, size_t ws_size,
                              hipStream_t stream) {
    const float* x      = (const float*)d_in[0];
    const float* gn_w   = (const float*)d_in[1];
    const float* gn_b   = (const float*)d_in[2];
    const float* qkv_w  = (const float*)d_in[3];
    const float* qkv_b  = (const float*)d_in[4];
    const float* proj_w = (const float*)d_in[5];
    const float* proj_b = (const float*)d_in[6];
    float* out = (float*)d_out;

    char* ws = (char*)d_ws;
    // region0 (33.5 MB) reused over time: hnT -> P_part (16 splits) -> attT
    bf16*  hnT    = (bf16*)ws;
    float* P_part = (float*)ws;                    // 16*32*16384 fp32 = 33.5 MB
    bf16*  attT   = (bf16*)ws;
    bf16*  qkbuf  = (bf16*)(ws + 33554432);        // [b][1024][4096] bf16 = 67.1 MB
    bf16*  vT     = (bf16*)(ws + 100663296);       // [b][4096][512]  bf16 = 33.5 MB
    bf16*  Pb     = (bf16*)(ws + 134217728);       // 32*128*128 bf16 = 1 MB
    float* stats  = (float*)(ws + 135266304);      // 256*2 fp32
    bf16*  qkv_wb = (bf16*)(ws + 135270400);       // 1536*512 bf16 = 1.5 MB
    bf16*  proj_wb= (bf16*)(ws + 136843264);       // 512*512 bf16 = 0.5 MB

    wconv2_kernel<<<1024, 256, 0, stream>>>(qkv_w, proj_w, qkv_wb, proj_wb);
    gn_stats_kernel<<<256, 1024, 0, stream>>>(x, stats);
    gn_norm_t_kernel<<<dim3(64, 8, 8), 256, 0, stream>>>(x, gn_w, gn_b, stats, hnT);
    qkv_gemm_kernel<<<dim3(16, 6, 8), 512, 0, stream>>>(hnT, qkv_wb, qkv_b, qkbuf, vT);
    qk_gemm_kernel<<<dim3(16, 32), 256, 0, stream>>>(qkbuf, P_part);
    softmax_kernel<<<4096, 128, 0, stream>>>(P_part, Pb);
    pv_gemm_kernel<<<dim3(32, 32), 256, 0, stream>>>(Pb, vT, attT);
    proj_gemm_kernel<<<dim3(16, 2, 8), 512, 0, stream>>>(attT, proj_wb, proj_b, x, out);
}

// Round 10
// 283.852 us; speedup vs baseline: 1.2340x; 1.0084x over previous
//
#include <hip/hip_runtime.h>
#include <hip/hip_bf16.h>

typedef __hip_bfloat16 bf16;
typedef __bf16 v8bf __attribute__((ext_vector_type(8)));
typedef float  v4f  __attribute__((ext_vector_type(4)));

struct __align__(8) bf16x4 { bf16 x, y, z, w; };

__device__ __forceinline__ bf16 f2b(float v) { return __float2bfloat16(v); }

// B=8, C=512, H=W=64 -> N=4096, HEADS=4, d=128, GROUPS=32
#define NSP 4096
#define CCH 512

// Async 16B global -> LDS (gfx950 direct-to-LDS, wave-uniform base + lane*16).
__device__ __forceinline__ void async_cp16(const bf16* g, __bf16* l) {
    __builtin_amdgcn_global_load_lds(
        (const __attribute__((address_space(1))) unsigned int*)(unsigned long long)g,
        (__attribute__((address_space(3))) unsigned int*)(unsigned int)(unsigned long long)l,
        16, 0, 0);
}

// ---------------------------------------------------------------------------
// Weight fp32 -> bf16 conversion, both weight tensors in one launch.
// ---------------------------------------------------------------------------
__global__ __launch_bounds__(256) void wconv2_kernel(const float* __restrict__ qw,
                                                     const float* __restrict__ pw,
                                                     bf16* __restrict__ qd,
                                                     bf16* __restrict__ pd) {
    int i = blockIdx.x * 256 + threadIdx.x;
    if (i < 196608) {
        float4 v = ((const float4*)qw)[i];
        bf16x4 o = { f2b(v.x), f2b(v.y), f2b(v.z), f2b(v.w) };
        ((bf16x4*)qd)[i] = o;
    } else {
        int j = i - 196608;
        float4 v = ((const float4*)pw)[j];
        bf16x4 o = { f2b(v.x), f2b(v.y), f2b(v.z), f2b(v.w) };
        ((bf16x4*)pd)[j] = o;
    }
}

// ---------------------------------------------------------------------------
// GN pass 1: per-(b,group) mean/rstd. 256 blocks x 1024 threads (16 waves).
// ---------------------------------------------------------------------------
__global__ __launch_bounds__(1024) void gn_stats_kernel(const float* __restrict__ x,
                                                        float* __restrict__ stats) {
    int blk = blockIdx.x;
    int b = blk >> 5, g = blk & 31;
    size_t base = ((size_t)(b * CCH + g * 16)) * NSP;     // 65536 floats
    const float4* xp4 = (const float4*)(x + base);
    int t = threadIdx.x;
    float s = 0.f, s2 = 0.f;
    for (int i = t; i < 16384; i += 1024) {
        float4 v = xp4[i];
        s  += v.x + v.y + v.z + v.w;
        s2 += v.x * v.x + v.y * v.y + v.z * v.z + v.w * v.w;
    }
    for (int off = 32; off > 0; off >>= 1) {
        s  += __shfl_down(s, off);
        s2 += __shfl_down(s2, off);
    }
    __shared__ float red[32];
    int wid = t >> 6, lid = t & 63;
    if (lid == 0) { red[wid] = s; red[wid + 16] = s2; }
    __syncthreads();
    if (t == 0) {
        float ts = 0.f, ts2 = 0.f;
#pragma unroll
        for (int w = 0; w < 16; ++w) { ts += red[w]; ts2 += red[w + 16]; }
        float mean = ts * (1.f / 65536.f);
        float var  = ts2 * (1.f / 65536.f) - mean * mean;
        stats[blk * 2]     = mean;
        stats[blk * 2 + 1] = rsqrtf(var + 1e-5f);
    }
}

// ---------------------------------------------------------------------------
// GN pass 2: normalize + transpose to n-major hnT[b][n][c] (bf16).
// ---------------------------------------------------------------------------
__global__ __launch_bounds__(256) void gn_norm_t_kernel(const float* __restrict__ x,
                                                        const float* __restrict__ gw,
                                                        const float* __restrict__ gb,
                                                        const float* __restrict__ stats,
                                                        bf16* __restrict__ hnT) {
    __shared__ float sT[64][65];
    int n0 = blockIdx.x * 64, c0 = blockIdx.y * 64, b = blockIdx.z;
    int t = threadIdx.x;
    int cl = t >> 4, nl4 = (t & 15) << 2;
#pragma unroll
    for (int it = 0; it < 4; ++it) {
        int crow = cl + it * 16;
        int c = c0 + crow;
        int bg = b * 32 + (c >> 4);
        float mean = stats[bg * 2], rstd = stats[bg * 2 + 1];
        float wsc = gw[c] * rstd;
        float bb  = gb[c] - mean * wsc;
        float4 v = *(const float4*)&x[((long)b * CCH + c) * NSP + n0 + nl4];
        sT[crow][nl4 + 0] = v.x * wsc + bb;
        sT[crow][nl4 + 1] = v.y * wsc + bb;
        sT[crow][nl4 + 2] = v.z * wsc + bb;
        sT[crow][nl4 + 3] = v.w * wsc + bb;
    }
    __syncthreads();
    int nl = t >> 4, cl4 = (t & 15) << 2;
#pragma unroll
    for (int it = 0; it < 4; ++it) {
        int nrow = nl + it * 16;
        bf16x4 ov = { f2b(sT[cl4 + 0][nrow]), f2b(sT[cl4 + 1][nrow]),
                      f2b(sT[cl4 + 2][nrow]), f2b(sT[cl4 + 3][nrow]) };
        *(bf16x4*)&hnT[((long)b * NSP + n0 + nrow) * CCH + c0 + cl4] = ov;
    }
}

// ---------------------------------------------------------------------------
// OLD MFMA GEMM core (m97 structure): used by QK^T and PV.
// 128x128 tile, BK=32, 256 threads (4 waves 2x2).
// ---------------------------------------------------------------------------
__device__ __forceinline__ void gemm_core(const bf16* __restrict__ A, long as,
                                          const bf16* __restrict__ B, long bs,
                                          int K, v4f acc[4][4],
                                          __bf16* sA, __bf16* sB) {
    int t = threadIdx.x;
    int lane = t & 63, wv = t >> 6;
    int wr = wv >> 1, wc = wv & 1;
    int lq = lane & 15, quad = lane >> 4;
    int r0 = wv * 16 + (lane >> 2);      // staging row, issue 0
    int koff = (lane & 3) * 8;           // staging k offset (elements)
    __bf16* ldsA0 = sA + wv * 512 + lane * 8;
    __bf16* ldsA1 = ldsA0 + 2048;
    __bf16* ldsB0 = sB + wv * 512 + lane * 8;
    __bf16* ldsB1 = ldsB0 + 2048;
    const __bf16* aBase = sA + (wr * 64) * 32;
    const __bf16* bBase = sB + (wc * 64) * 32;

    for (int k0 = 0; k0 < K; k0 += 32) {
        __syncthreads();                 // prior-iteration LDS reads done
        async_cp16(A + (long)r0 * as + k0 + koff,        ldsA0);
        async_cp16(A + (long)(r0 + 64) * as + k0 + koff, ldsA1);
        async_cp16(B + (long)r0 * bs + k0 + koff,        ldsB0);
        async_cp16(B + (long)(r0 + 64) * bs + k0 + koff, ldsB1);
        __syncthreads();                 // vmcnt drained at barrier -> data visible
        v8bf a[4], bf[4];
#pragma unroll
        for (int i = 0; i < 4; ++i)
            a[i] = *(const v8bf*)(aBase + (i * 16 + lq) * 32 + quad * 8);
#pragma unroll
        for (int j = 0; j < 4; ++j)
            bf[j] = *(const v8bf*)(bBase + (j * 16 + lq) * 32 + quad * 8);
#pragma unroll
        for (int i = 0; i < 4; ++i)
#pragma unroll
            for (int j = 0; j < 4; ++j)
                acc[i][j] = __builtin_amdgcn_mfma_f32_16x16x32_bf16(a[i], bf[j], acc[i][j], 0, 0, 0);
    }
}

// ---------------------------------------------------------------------------
// 256x256 GEMM core — RELAXED schedule (r5/r8, best measured: qkv 68.6us).
//   Phase = { ds_read quadrant; STAGE (prefetch); setprio(1) MFMA x16
//             setprio(0); barrier }.  No mid-phase barrier / lgkmcnt(0):
//   each phase's ds_reads are consumed by its own MFMAs (compiler lgkm
//   waits); trailing reads drain under MFMA.
//   Stage: ph1/2 -> T{k+1}.A halves (nxt buf); ph3/4 -> T{k+2}.B halves (cur).
//   Boundary vmcnt(4). Swizzle byte^=((row&7)<<4) src-side + ds_read-side.
// ---------------------------------------------------------------------------
__device__ __forceinline__ void gemm256_core(const bf16* __restrict__ A, long lda,
                                             const bf16* __restrict__ B, long ldb,
                                             int K, v4f acc[8][4], char* sLds) {
    const int t = threadIdx.x;
    const int lane = t & 63, wv = t >> 6;
    const int wm = wv >> 2, wn = wv & 3;
    const int lq = lane & 15, quad = lane >> 4;
    const int xsw = (lq & 7) << 4;
    const int kq0 = ((quad << 4)) ^ xsw;
    const int kq1 = (64 | (quad << 4)) ^ xsw;
    const int aRow0 = (wm * 128 + lq) << 7;
    const int bRow0 = (wn * 64 + lq) << 7;
    const int NT = K >> 6;

    auto STAGE = [&](const bf16* mb, long ld, int ldsbyte, int ktile, int h) {
#pragma unroll
        for (int s = 0; s < 2; ++s) {
            int L = (s << 13) + (t << 4);
            int row = L >> 7;
            int kb = (L & 127) ^ ((row & 7) << 4);
            const char* g = (const char*)(mb + (long)(h * 128 + row) * ld + (long)ktile * 64);
            async_cp16((const bf16*)(g + kb),
                       (__bf16*)(sLds + ldsbyte + (h << 14) + L));
        }
    };

    STAGE(B, ldb, 32768, 0, 0);
    STAGE(B, ldb, 32768, 0, 1);
    STAGE(A, lda, 0,     0, 0);
    STAGE(A, lda, 0,     0, 1);
    if (NT > 1) {
        STAGE(B, ldb, 65536 + 32768, 1, 0);
        STAGE(B, ldb, 65536 + 32768, 1, 1);
        asm volatile("s_waitcnt vmcnt(4)" ::: "memory");
    } else {
        asm volatile("s_waitcnt vmcnt(0)" ::: "memory");
    }
    __builtin_amdgcn_s_barrier();
    asm volatile("" ::: "memory");

    for (int kt = 0; kt < NT; ++kt) {
        const int cb = (kt & 1) << 16;
        const int nb = cb ^ 65536;
        const int bufA = cb, bufB = cb | 32768;
        v8bf a[4][2], b0[2][2], b1[2][2];

        // ---- phase 1: read A-quad0 + B-quad0; stage T{k+1}.A0; MFMA C(m0,n0)
#pragma unroll
        for (int ii = 0; ii < 4; ++ii) {
            a[ii][0] = *(const v8bf*)(sLds + bufA + aRow0 + ((ii * 16) << 7) + kq0);
            a[ii][1] = *(const v8bf*)(sLds + bufA + aRow0 + ((ii * 16) << 7) + kq1);
        }
#pragma unroll
        for (int jj = 0; jj < 2; ++jj) {
            b0[jj][0] = *(const v8bf*)(sLds + bufB + bRow0 + ((jj * 16) << 7) + kq0);
            b0[jj][1] = *(const v8bf*)(sLds + bufB + bRow0 + ((jj * 16) << 7) + kq1);
        }
        if (kt + 1 < NT) STAGE(A, lda, nb, kt + 1, 0);
        __builtin_amdgcn_s_setprio(1);
#pragma unroll
        for (int ii = 0; ii < 4; ++ii)
#pragma unroll
            for (int jj = 0; jj < 2; ++jj) {
                acc[ii][jj] = __builtin_amdgcn_mfma_f32_16x16x32_bf16(a[ii][0], b0[jj][0], acc[ii][jj], 0, 0, 0);
                acc[ii][jj] = __builtin_amdgcn_mfma_f32_16x16x32_bf16(a[ii][1], b0[jj][1], acc[ii][jj], 0, 0, 0);
            }
        __builtin_amdgcn_s_setprio(0);
        __builtin_amdgcn_s_barrier();
        asm volatile("" ::: "memory");

        // ---- phase 2: read B-quad1; stage T{k+1}.A1; MFMA C(m0,n1), reuse a
#pragma unroll
        for (int jj = 0; jj < 2; ++jj) {
            b1[jj][0] = *(const v8bf*)(sLds + bufB + bRow0 + ((32 + jj * 16) << 7) + kq0);
            b1[jj][1] = *(const v8bf*)(sLds + bufB + bRow0 + ((32 + jj * 16) << 7) + kq1);
        }
        if (kt + 1 < NT) STAGE(A, lda, nb, kt + 1, 1);
        __builtin_amdgcn_s_setprio(1);
#pragma unroll
        for (int ii = 0; ii < 4; ++ii)
#pragma unroll
            for (int jj = 0; jj < 2; ++jj) {
                acc[ii][2 + jj] = __builtin_amdgcn_mfma_f32_16x16x32_bf16(a[ii][0], b1[jj][0], acc[ii][2 + jj], 0, 0, 0);
                acc[ii][2 + jj] = __builtin_amdgcn_mfma_f32_16x16x32_bf16(a[ii][1], b1[jj][1], acc[ii][2 + jj], 0, 0, 0);
            }
        __builtin_amdgcn_s_setprio(0);
        __builtin_amdgcn_s_barrier();
        asm volatile("" ::: "memory");

        // ---- phase 3: read A-quad1; stage T{k+2}.B0 (cur bufB); MFMA C(m1,n1)
#pragma unroll
        for (int ii = 0; ii < 4; ++ii) {
            a[ii][0] = *(const v8bf*)(sLds + bufA + aRow0 + ((64 + ii * 16) << 7) + kq0);
            a[ii][1] = *(const v8bf*)(sLds + bufA + aRow0 + ((64 + ii * 16) << 7) + kq1);
        }
        if (kt + 2 < NT) STAGE(B, ldb, bufB, kt + 2, 0);
        __builtin_amdgcn_s_setprio(1);
#pragma unroll
        for (int ii = 0; ii < 4; ++ii)
#pragma unroll
            for (int jj = 0; jj < 2; ++jj) {
                acc[4 + ii][2 + jj] = __builtin_amdgcn_mfma_f32_16x16x32_bf16(a[ii][0], b1[jj][0], acc[4 + ii][2 + jj], 0, 0, 0);
                acc[4 + ii][2 + jj] = __builtin_amdgcn_mfma_f32_16x16x32_bf16(a[ii][1], b1[jj][1], acc[4 + ii][2 + jj], 0, 0, 0);
            }
        __builtin_amdgcn_s_setprio(0);
        __builtin_amdgcn_s_barrier();
        asm volatile("" ::: "memory");

        // ---- phase 4: stage T{k+2}.B1; MFMA C(m1,n0), reuse a + b0 ----
        if (kt + 2 < NT) STAGE(B, ldb, bufB, kt + 2, 1);
        __builtin_amdgcn_s_setprio(1);
#pragma unroll
        for (int ii = 0; ii < 4; ++ii)
#pragma unroll
            for (int jj = 0; jj < 2; ++jj) {
                acc[4 + ii][jj] = __builtin_amdgcn_mfma_f32_16x16x32_bf16(a[ii][0], b0[jj][0], acc[4 + ii][jj], 0, 0, 0);
                acc[4 + ii][jj] = __builtin_amdgcn_mfma_f32_16x16x32_bf16(a[ii][1], b0[jj][1], acc[4 + ii][jj], 0, 0, 0);
            }
        __builtin_amdgcn_s_setprio(0);
        if (kt + 2 < NT) asm volatile("s_waitcnt vmcnt(4)" ::: "memory");
        else             asm volatile("s_waitcnt vmcnt(0)" ::: "memory");
        __builtin_amdgcn_s_barrier();
        asm volatile("" ::: "memory");
    }
}

// ---------------------------------------------------------------------------
// QKV GEMM (swapped): D[n][o] = sum_k hnT[n][k] * Wqkv[o][k]  (+bias)
// q,k (o<1024) -> qkbuf[b][o][n]; v (o>=1024) -> vT[b][n][e].
// 256x256 tiles: grid (16 n-tiles, 6 o-tiles, 8 b), 512 threads.
// ---------------------------------------------------------------------------
__global__ __launch_bounds__(512, 2) void qkv_gemm_kernel(const bf16* __restrict__ hnT,
                                                          const bf16* __restrict__ qkv_wb,
                                                          const float* __restrict__ qkv_b,
                                                          bf16* __restrict__ qkbuf,
                                                          bf16* __restrict__ vT) {
    __shared__ __align__(16) char sLds[131072];
    int n0 = blockIdx.x * 256, o0 = blockIdx.y * 256, b = blockIdx.z;
    v4f acc[8][4] = {};
    gemm256_core(hnT + ((long)b * NSP + n0) * CCH, CCH,
                 qkv_wb + (long)o0 * CCH, CCH, CCH, acc, sLds);
    int t = threadIdx.x, lane = t & 63, wv = t >> 6, wm = wv >> 2, wn = wv & 3;
    int lq = lane & 15, quad = lane >> 4;
    if (o0 < 1024) {
#pragma unroll
        for (int j = 0; j < 4; ++j) {
            int o = o0 + wn * 64 + j * 16 + lq;
            float bias = qkv_b[o];
#pragma unroll
            for (int i = 0; i < 8; ++i) {
                int n = n0 + wm * 128 + i * 16 + quad * 4;
                v4f v = acc[i][j];
                bf16x4 ov = { f2b(v[0] + bias), f2b(v[1] + bias),
                              f2b(v[2] + bias), f2b(v[3] + bias) };
                *(bf16x4*)&qkbuf[((long)b * 1024 + o) * NSP + n] = ov;
            }
        }
    } else {
#pragma unroll
        for (int j = 0; j < 4; ++j) {
            int e = o0 - 1024 + wn * 64 + j * 16 + lq;
            float bias = qkv_b[1024 + e];
#pragma unroll
            for (int i = 0; i < 8; ++i) {
                int n = n0 + wm * 128 + i * 16 + quad * 4;
                v4f v = acc[i][j];
#pragma unroll
                for (int r = 0; r < 4; ++r)
                    vT[((long)b * NSP + n + r) * CCH + e] = f2b(v[r] + bias);
            }
        }
    }
}

// ---------------------------------------------------------------------------
// QK^T split-K 16: P_part[s][bh][d][e] = sum_{n in split} q[d][n]*k[e][n]
// grid (16 splits, 32 bh), K=256 each -> 512 blocks = 2 blocks/CU.
// ---------------------------------------------------------------------------
__global__ __launch_bounds__(256) void qk_gemm_kernel(const bf16* __restrict__ qkbuf,
                                                      float* __restrict__ P_part) {
    __shared__ __align__(16) __bf16 sA[128 * 32];
    __shared__ __align__(16) __bf16 sB[128 * 32];
    int s = blockIdx.x, bh = blockIdx.y;
    int b = bh >> 2, h = bh & 3;
    const bf16* q  = qkbuf + ((long)b * 1024 + h * 128) * NSP + s * 256;
    const bf16* kk = qkbuf + ((long)b * 1024 + 512 + h * 128) * NSP + s * 256;
    v4f acc[4][4] = {};
    gemm_core(q, NSP, kk, NSP, 256, acc, sA, sB);
    float* Pp = P_part + ((long)s * 32 + bh) * 16384;
    int t = threadIdx.x, lane = t & 63, wv = t >> 6, wr = wv >> 1, wc = wv & 1;
    int lq = lane & 15, quad = lane >> 4;
#pragma unroll
    for (int j = 0; j < 4; ++j) {
        int e = wc * 64 + j * 16 + lq;
#pragma unroll
        for (int i = 0; i < 4; ++i) {
            int d = wr * 64 + i * 16 + quad * 4;
            v4f v = acc[i][j];
#pragma unroll
            for (int r = 0; r < 4; ++r) Pp[(long)(d + r) * 128 + e] = v[r];
        }
    }
}

// ---------------------------------------------------------------------------
// Softmax: sum 16 partials, scale by d^-0.5, softmax over e, emit bf16 P.
// ---------------------------------------------------------------------------
__global__ __launch_bounds__(128) void softmax_kernel(const float* __restrict__ P_part,
                                                      bf16* __restrict__ Pb) {
    int row = blockIdx.x;
    int bh = row >> 7, d = row & 127;
    int t = threadIdx.x;
    float v = 0.f;
#pragma unroll
    for (int s = 0; s < 16; ++s)
        v += P_part[((long)s * 32 + bh) * 16384 + (long)d * 128 + t];
    v *= 0.08838834764831845f;
    float m = v;
    for (int off = 32; off > 0; off >>= 1) m = fmaxf(m, __shfl_down(m, off));
    __shared__ float sm[2];
    if ((t & 63) == 0) sm[t >> 6] = m;
    __syncthreads();
    m = fmaxf(sm[0], sm[1]);
    float e = __expf(v - m);
    float ssum = e;
    for (int off = 32; off > 0; off >>= 1) ssum += __shfl_down(ssum, off);
    __shared__ float ss[2];
    if ((t & 63) == 0) ss[t >> 6] = ssum;
    __syncthreads();
    ssum = ss[0] + ss[1];
    Pb[(long)row * 128 + t] = f2b(e / ssum);
}

// ---------------------------------------------------------------------------
// PV (v1, old core — best measured): attT[b][n][h*128+d] = sum_e P[d][e]*vT[n][e]
// grid (32 n-tiles, 32 bh)
// ---------------------------------------------------------------------------
__global__ __launch_bounds__(256) void pv_gemm_kernel(const bf16* __restrict__ Pb,
                                                      const bf16* __restrict__ vT,
                                                      bf16* __restrict__ attT) {
    __shared__ __align__(16) __bf16 sA[128 * 32];
    __shared__ __align__(16) __bf16 sB[128 * 32];
    int n0 = blockIdx.x * 128, bh = blockIdx.y;
    int b = bh >> 2, h = bh & 3;
    v4f acc[4][4] = {};
    gemm_core(Pb + (long)bh * 16384, 128,
              vT + ((long)b * NSP + n0) * CCH + h * 128, CCH, 128, acc, sA, sB);
    int t = threadIdx.x, lane = t & 63, wv = t >> 6, wr = wv >> 1, wc = wv & 1;
    int lq = lane & 15, quad = lane >> 4;
#pragma unroll
    for (int j = 0; j < 4; ++j) {
        int n = n0 + wc * 64 + j * 16 + lq;
#pragma unroll
        for (int i = 0; i < 4; ++i) {
            int d = wr * 64 + i * 16 + quad * 4;
            v4f v = acc[i][j];
            bf16x4 ov = { f2b(v[0]), f2b(v[1]), f2b(v[2]), f2b(v[3]) };
            *(bf16x4*)&attT[((long)b * NSP + n) * CCH + h * 128 + d] = ov;
        }
    }
}

// ---------------------------------------------------------------------------
// Proj (swapped): out[b][c][n] = sum_k attT[n][k]*Wp[c][k] + bias[c] + x
// 256x256 tiles: grid (16 n-tiles, 2 c-tiles, 8 b), 512 threads.
// ---------------------------------------------------------------------------
__global__ __launch_bounds__(512, 2) void proj_gemm_kernel(const bf16* __restrict__ attT,
                                                           const bf16* __restrict__ proj_wb,
                                                           const float* __restrict__ proj_b,
                                                           const float* __restrict__ x,
                                                           float* __restrict__ out) {
    __shared__ __align__(16) char sLds[131072];
    int n0 = blockIdx.x * 256, c0 = blockIdx.y * 256, b = blockIdx.z;
    v4f acc[8][4] = {};
    gemm256_core(attT + ((long)b * NSP + n0) * CCH, CCH,
                 proj_wb + (long)c0 * CCH, CCH, CCH, acc, sLds);
    int t = threadIdx.x, lane = t & 63, wv = t >> 6, wm = wv >> 2, wn = wv & 3;
    int lq = lane & 15, quad = lane >> 4;
#pragma unroll
    for (int j = 0; j < 4; ++j) {
        int c = c0 + wn * 64 + j * 16 + lq;
        float bias = proj_b[c];
#pragma unroll
        for (int i = 0; i < 8; ++i) {
            int n = n0 + wm * 128 + i * 16 + quad * 4;
            long idx = ((long)b * CCH + c) * NSP + n;
            float4 r = *(const float4*)&x[idx];
            v4f v = acc[i][j];
            float4 ov = { v[0] + bias + r.x, v[1] + bias + r.y,
                          v[2] + bias + r.z, v[3] + bias + r.w };
            *(float4*)&out[idx] = ov;
        }
    }
}

// ---------------------------------------------------------------------------
extern "C" void kernel_launch(void* const* d_in, const int* in_sizes, int n_in,
                              void* d_out, int out_size, void* d_ws, size_t ws_size,
                              hipStream_t stream) {
    const float* x      = (const float*)d_in[0];
    const float* gn_w   = (const float*)d_in[1];
    const float* gn_b   = (const float*)d_in[2];
    const float* qkv_w  = (const float*)d_in[3];
    const float* qkv_b  = (const float*)d_in[4];
    const float* proj_w = (const float*)d_in[5];
    const float* proj_b = (const float*)d_in[6];
    float* out = (float*)d_out;

    char* ws = (char*)d_ws;
    // region0 (33.5 MB) reused over time: hnT -> P_part (16 splits) -> attT
    bf16*  hnT    = (bf16*)ws;
    float* P_part = (float*)ws;                    // 16*32*16384 fp32 = 33.5 MB
    bf16*  attT   = (bf16*)ws;
    bf16*  qkbuf  = (bf16*)(ws + 33554432);        // [b][1024][4096] bf16 = 67.1 MB
    bf16*  vT     = (bf16*)(ws + 100663296);       // [b][4096][512]  bf16 = 33.5 MB
    bf16*  Pb     = (bf16*)(ws + 134217728);       // 32*128*128 bf16 = 1 MB
    float* stats  = (float*)(ws + 135266304);      // 256*2 fp32
    bf16*  qkv_wb = (bf16*)(ws + 135270400);       // 1536*512 bf16 = 1.5 MB
    bf16*  proj_wb= (bf16*)(ws + 136843264);       // 512*512 bf16 = 0.5 MB

    wconv2_kernel<<<1024, 256, 0, stream>>>(qkv_w, proj_w, qkv_wb, proj_wb);
    gn_stats_kernel<<<256, 1024, 0, stream>>>(x, stats);
    gn_norm_t_kernel<<<dim3(64, 8, 8), 256, 0, stream>>>(x, gn_w, gn_b, stats, hnT);
    qkv_gemm_kernel<<<dim3(16, 6, 8), 512, 0, stream>>>(hnT, qkv_wb, qkv_b, qkbuf, vT);
    qk_gemm_kernel<<<dim3(16, 32), 256, 0, stream>>>(qkbuf, P_part);
    softmax_kernel<<<4096, 128, 0, stream>>>(P_part, Pb);
    pv_gemm_kernel<<<dim3(32, 32), 256, 0, stream>>>(Pb, vT, attT);
    proj_gemm_kernel<<<dim3(16, 2, 8), 512, 0, stream>>>(attT, proj_wb, proj_b, x, out);
}